// Round 11
// baseline (696.359 us; speedup 1.0000x reference)
//
#include <hip/hip_runtime.h>

typedef unsigned short u16;
typedef __attribute__((ext_vector_type(8))) short s16x8;
typedef __attribute__((ext_vector_type(8))) unsigned short u16x8;
typedef __attribute__((ext_vector_type(4))) unsigned short u16x4;
typedef __attribute__((ext_vector_type(4))) float f32x4;

#define DEV static __device__ __forceinline__
#define MFMA __builtin_amdgcn_mfma_f32_16x16x32_bf16

DEV float bf2f(u16 u) { return __uint_as_float(((unsigned)u) << 16); }
DEV u16 f2bf(float f) {
    unsigned u = __float_as_uint(f);
    return (u16)((u + 0x7FFFu + ((u >> 16) & 1u)) >> 16);
}
DEV void split2(float v, u16& hi, u16& lo) {
    hi = f2bf(v);
    lo = f2bf(v - bf2f(hi));
}

// ===========================================================================
// bf16 hi/lo plane pipeline kernels (verified R5/R13)
// ===========================================================================

// Split fp32 -> bf16 hi/lo planes, elementwise. n multiple of 2048.
__global__ __launch_bounds__(256) void split_k(
    const float* __restrict__ src, u16* __restrict__ dh, u16* __restrict__ dl, long n)
{
    const long i = ((long)blockIdx.x * 256 + threadIdx.x) * 8;
    if (i >= n) return;
    float4 f0 = *(const float4*)(src + i);
    float4 f1 = *(const float4*)(src + i + 4);
    float v[8] = {f0.x, f0.y, f0.z, f0.w, f1.x, f1.y, f1.z, f1.w};
    u16x8 h8, l8;
    for (int j = 0; j < 8; ++j) { u16 hh, ll; split2(v[j], hh, ll); h8[j] = hh; l8[j] = ll; }
    *(u16x8*)(dh + i) = h8;
    *(u16x8*)(dl + i) = l8;
}

// Transpose+split (hi only): src [E][K][N] fp32 -> dst [E][N][K] bf16.
__global__ __launch_bounds__(256) void splitT_k(
    const float* __restrict__ src, u16* __restrict__ dst, int K, int N)
{
    __shared__ u16 tile[64 * 72];
    const int e = blockIdx.z;
    const int n0 = blockIdx.x * 64, k0 = blockIdx.y * 64;
    const long estride = (long)K * N;
    const int tid = threadIdx.x;
    const int tr = tid >> 2, tc = (tid & 3) * 16;
    {
        const float* sp = src + e * estride + (long)(k0 + tr) * N + n0 + tc;
        for (int j = 0; j < 16; j += 4) {
            float4 f = *(const float4*)(sp + j);
            tile[tr * 72 + tc + j + 0] = f2bf(f.x);
            tile[tr * 72 + tc + j + 1] = f2bf(f.y);
            tile[tr * 72 + tc + j + 2] = f2bf(f.z);
            tile[tr * 72 + tc + j + 3] = f2bf(f.w);
        }
    }
    __syncthreads();
    {
        const int tn = tid >> 2, tk = (tid & 3) * 16;
        u16* dp = dst + e * estride + (long)(n0 + tn) * K + k0 + tk;
        u16x8 o0, o1;
        for (int j = 0; j < 8; ++j) {
            o0[j] = tile[(tk + j) * 72 + tn];
            o1[j] = tile[(tk + 8 + j) * 72 + tn];
        }
        *(u16x8*)(dp) = o0;
        *(u16x8*)(dp + 8) = o1;
    }
}

// ---------------------------------------------------------------------------
// GEMM (plane pipeline): C = act(A @ B^T + bias).
// R13: LDS stride 36 u16 (72B rows -> conflict-free ds_read_b128; verified
// 12.6M -> ~0 conflict cycles).
// ---------------------------------------------------------------------------
__global__ __launch_bounds__(256) void gemm_s(
    const float* __restrict__ Af, const u16* __restrict__ Ahp, const u16* __restrict__ Alp,
    int lda, int a_lo, const int* __restrict__ perm_in,
    const u16* __restrict__ Bh, const u16* __restrict__ Bl, int ldb, long b_estride,
    const int* __restrict__ tile_expert,
    const float* __restrict__ bias, int bias_estride,
    float* __restrict__ Cf, int ldcf, const int* __restrict__ perm_out,
    u16* __restrict__ Ch, long clo_off, int ldcp, int ts, long tstride,
    int K, int act)
{
    __shared__ u16 As[64 * 36], Als[64 * 36];
    __shared__ u16 Bs[64 * 36], Bls[64 * 36];
    const int mt = blockIdx.x, nt = blockIdx.y;
    int e = 0;
    if (tile_expert) { e = tile_expert[mt]; if (e < 0) return; }
    const int tid = threadIdx.x, lane = tid & 63, w = tid >> 6;
    const int wr = (w >> 1) * 32, wc = (w & 1) * 32;
    const int quad = lane >> 4, l15 = lane & 15;
    const int b_lo = (Bl != nullptr);

    const u16* Bhb = Bh + (long)e * b_estride;
    const u16* Blb = b_lo ? (Bl + (long)e * b_estride) : nullptr;

    const int r2 = tid >> 3, c4 = (tid & 7) * 4;   // fp32-A staging
    const int r1 = tid >> 2, c8 = (tid & 3) * 8;   // plane staging
    long arow0 = 0, arow1 = 0, arowb = 0;
    bool v0 = true, v1 = true, vb = true;
    if (perm_in) {
        if (Af) {
            int p0 = perm_in[mt * 64 + r2];      v0 = p0 >= 0; arow0 = p0 < 0 ? 0 : p0;
            int p1 = perm_in[mt * 64 + r2 + 32]; v1 = p1 >= 0; arow1 = p1 < 0 ? 0 : p1;
        } else {
            int pb = perm_in[mt * 64 + r1];      vb = pb >= 0; arowb = pb < 0 ? 0 : pb;
        }
    } else {
        arow0 = (long)mt * 64 + r2; arow1 = arow0 + 32; arowb = (long)mt * 64 + r1;
    }

    f32x4 acc[2][2] = {};

    for (int k0 = 0; k0 < K; k0 += 32) {
        __syncthreads();
        if (Af) {
            for (int half = 0; half < 2; ++half) {
                const int row = half * 32 + r2;
                const long ar = half ? arow1 : arow0;
                const bool va = half ? v1 : v0;
                float4 v = va ? *(const float4*)(Af + ar * (long)lda + k0 + c4)
                              : make_float4(0.f, 0.f, 0.f, 0.f);
                float vv[4] = {v.x, v.y, v.z, v.w};
                u16x4 h4, l4;
                for (int i = 0; i < 4; ++i) { u16 hh, ll; split2(vv[i], hh, ll); h4[i] = hh; l4[i] = ll; }
                *(u16x4*)&As[row * 36 + c4] = h4;
                if (a_lo) *(u16x4*)&Als[row * 36 + c4] = l4;
            }
        } else {
            const long ao = arowb * (long)lda + k0 + c8;
            u16x8 h8 = vb ? *(const u16x8*)(Ahp + ao) : (u16x8)(u16)0;
            *(u16x8*)&As[r1 * 36 + c8] = h8;
            if (a_lo) {
                u16x8 l8 = vb ? *(const u16x8*)(Alp + ao) : (u16x8)(u16)0;
                *(u16x8*)&Als[r1 * 36 + c8] = l8;
            }
        }
        {
            const long bo = ((long)nt * 64 + r1) * ldb + k0 + c8;
            *(u16x8*)&Bs[r1 * 36 + c8] = *(const u16x8*)(Bhb + bo);
            if (b_lo) *(u16x8*)&Bls[r1 * 36 + c8] = *(const u16x8*)(Blb + bo);
        }
        __syncthreads();
        s16x8 ah0 = *(const s16x8*)&As[(wr + l15) * 36 + quad * 8];
        s16x8 ah1 = *(const s16x8*)&As[(wr + 16 + l15) * 36 + quad * 8];
        s16x8 bh0 = *(const s16x8*)&Bs[(wc + l15) * 36 + quad * 8];
        s16x8 bh1 = *(const s16x8*)&Bs[(wc + 16 + l15) * 36 + quad * 8];
        acc[0][0] = MFMA(ah0, bh0, acc[0][0], 0, 0, 0);
        acc[0][1] = MFMA(ah0, bh1, acc[0][1], 0, 0, 0);
        acc[1][0] = MFMA(ah1, bh0, acc[1][0], 0, 0, 0);
        acc[1][1] = MFMA(ah1, bh1, acc[1][1], 0, 0, 0);
        if (a_lo) {
            s16x8 al0 = *(const s16x8*)&Als[(wr + l15) * 36 + quad * 8];
            s16x8 al1 = *(const s16x8*)&Als[(wr + 16 + l15) * 36 + quad * 8];
            acc[0][0] = MFMA(al0, bh0, acc[0][0], 0, 0, 0);
            acc[0][1] = MFMA(al0, bh1, acc[0][1], 0, 0, 0);
            acc[1][0] = MFMA(al1, bh0, acc[1][0], 0, 0, 0);
            acc[1][1] = MFMA(al1, bh1, acc[1][1], 0, 0, 0);
        }
        if (b_lo) {
            s16x8 bl0 = *(const s16x8*)&Bls[(wc + l15) * 36 + quad * 8];
            s16x8 bl1 = *(const s16x8*)&Bls[(wc + 16 + l15) * 36 + quad * 8];
            acc[0][0] = MFMA(ah0, bl0, acc[0][0], 0, 0, 0);
            acc[0][1] = MFMA(ah0, bl1, acc[0][1], 0, 0, 0);
            acc[1][0] = MFMA(ah1, bl0, acc[1][0], 0, 0, 0);
            acc[1][1] = MFMA(ah1, bl1, acc[1][1], 0, 0, 0);
        }
    }

    const float* bp = bias + (long)e * bias_estride;
    for (int mi = 0; mi < 2; ++mi) {
        for (int r = 0; r < 4; ++r) {
            const int rloc = wr + mi * 16 + quad * 4 + r;  // C/D: row=(lane>>4)*4+reg
            const long lrow = (long)mt * 64 + rloc;
            for (int ni = 0; ni < 2; ++ni) {
                const int colg = nt * 64 + wc + ni * 16 + l15;  // C/D: col=lane&15
                float v = acc[mi][ni][r] + bp[colg];
                if (act == 1) v = 0.5f * v * (1.f + erff(v * 0.7071067811865475f));
                if (Cf) {
                    long orow = lrow;
                    if (perm_out) { int po = perm_out[mt * 64 + rloc]; if (po < 0) continue; orow = po; }
                    Cf[orow * (long)ldcf + colg] = v;
                }
                if (Ch) {
                    const int t = colg >> ts;
                    const int cc = colg - (t << ts);
                    const long po = (long)t * tstride + lrow * (long)ldcp + cc;
                    u16 hh, ll; split2(v, hh, ll);
                    Ch[po] = hh;
                    if (clo_off) Ch[po + clo_off] = ll;
                }
            }
        }
    }
}

// ---------------------------------------------------------------------------
// Flash attention, single-plane bf16 (R12/R13 verified: swapped QK^T,
// max-free softmax, dual 32-key chains, KVBLK=64 double-buffered, XCD
// swizzle, sc folded into Q, truncation pack). R15 runs it at z=4
// (1024 blocks = 4 blk/CU) in the PROVEN R5 memory layout.
// ---------------------------------------------------------------------------
__global__ __launch_bounds__(256) void attn_p(
    const u16* __restrict__ Qh, const u16* __restrict__ Kh, const u16* __restrict__ Vh,
    long plo, u16* __restrict__ Oh, long olo, int orow_base, float sc)
{
    (void)plo;
    __shared__ u16 Khs[2][64 * 80];     // [buf][64 keys x 64 dims]
    __shared__ u16 Vhs[2][2][64 * 36];  // [buf][key-half][64 dims x 32 slots]
    // XCD swizzle: cluster the 32 qt blocks of one (z,h) onto one XCD.
    const int Z = gridDim.z;
    const int lin = blockIdx.x + 32 * (blockIdx.y + 8 * blockIdx.z);
    const int g = lin & 7, li = lin >> 3;
    const int p = g * Z + (li >> 5);
    const int qt = li & 31;
    const int h = p & 7, z = p >> 3;

    const int tid = threadIdx.x, lane = tid & 63, w = tid >> 6;
    const int quad = lane >> 4, l15 = lane & 15;

    // Q fragment (B-operand of swapped QK^T), pre-scaled by sc.
    const long qoff = ((long)z * 2048 + qt * 64 + w * 16 + l15) * 512 + h * 64 + quad * 8;
    s16x8 q0, q1;
    {
        s16x8 q0r = *(const s16x8*)(Qh + qoff);
        s16x8 q1r = *(const s16x8*)(Qh + qoff + 32);
        #pragma unroll
        for (int j = 0; j < 8; ++j) {
            q0[j] = (short)f2bf(bf2f((u16)q0r[j]) * sc);
            q1[j] = (short)f2bf(bf2f((u16)q1r[j]) * sc);
        }
    }

    const int kr = tid >> 3, kc = (tid & 7) * 8;       // K stage: rows kr, kr+32
    const int vkey = tid & 31, vhd0 = (tid >> 5) * 8;  // V stage: keys vkey, vkey+32
    // PV A-frag keyslot(quad,j) = quad*4+(j&3)+16*(j>>2); sigma = inverse (R9).
    const int vslot = ((vkey >> 2) & 3) * 8 + (vkey & 3) + ((vkey >> 4) << 2);
    const long kbase = ((long)z * 2048 + kr) * 512 + h * 64 + kc;
    const long vbase = ((long)z * 2048 + vkey) * 512 + h * 64 + vhd0;

    // prologue: stage tile 0 (keys 0..63) into buffer 0
    {
        u16x8 ka = *(const u16x8*)(Kh + kbase);
        u16x8 kb = *(const u16x8*)(Kh + kbase + 32L * 512);
        u16x8 va = *(const u16x8*)(Vh + vbase);
        u16x8 vb = *(const u16x8*)(Vh + vbase + 32L * 512);
        *(u16x8*)&Khs[0][kr * 80 + kc] = ka;
        *(u16x8*)&Khs[0][(kr + 32) * 80 + kc] = kb;
        #pragma unroll
        for (int i = 0; i < 8; ++i) {
            Vhs[0][0][(vhd0 + i) * 36 + vslot] = va[i];
            Vhs[0][1][(vhd0 + i) * 36 + vslot] = vb[i];
        }
    }

    float l_run = 0.f;
    f32x4 oacc[4] = {};

    for (int t = 0; t < 32; ++t) {
        const int cur = t & 1;
        __syncthreads();   // buf[cur] staged & visible
        u16x8 kna, knb, vna, vnb;
        if (t < 31) {
            const long o = (long)(t + 1) * 32768;   // 64 keys * 512 dims
            kna = *(const u16x8*)(Kh + kbase + o);
            knb = *(const u16x8*)(Kh + kbase + 32L * 512 + o);
            vna = *(const u16x8*)(Vh + vbase + o);
            vnb = *(const u16x8*)(Vh + vbase + 32L * 512 + o);
        }
        const u16* Kc = Khs[cur];
        // ---- two independent 32-key chains ----
        f32x4 s0a = {0.f, 0.f, 0.f, 0.f}, s1a = {0.f, 0.f, 0.f, 0.f};
        f32x4 s0b = {0.f, 0.f, 0.f, 0.f}, s1b = {0.f, 0.f, 0.f, 0.f};
        {
            s16x8 a00 = *(const s16x8*)&Kc[l15 * 80 + quad * 8];
            s16x8 a01 = *(const s16x8*)&Kc[l15 * 80 + 32 + quad * 8];
            s16x8 a10 = *(const s16x8*)&Kc[(16 + l15) * 80 + quad * 8];
            s16x8 a11 = *(const s16x8*)&Kc[(16 + l15) * 80 + 32 + quad * 8];
            s16x8 b00 = *(const s16x8*)&Kc[(32 + l15) * 80 + quad * 8];
            s16x8 b01 = *(const s16x8*)&Kc[(32 + l15) * 80 + 32 + quad * 8];
            s16x8 b10 = *(const s16x8*)&Kc[(48 + l15) * 80 + quad * 8];
            s16x8 b11 = *(const s16x8*)&Kc[(48 + l15) * 80 + 32 + quad * 8];
            __builtin_amdgcn_s_setprio(1);
            s0a = MFMA(a00, q0, s0a, 0, 0, 0);
            s1a = MFMA(a10, q0, s1a, 0, 0, 0);
            s0b = MFMA(b00, q0, s0b, 0, 0, 0);
            s1b = MFMA(b10, q0, s1b, 0, 0, 0);
            s0a = MFMA(a01, q1, s0a, 0, 0, 0);
            s1a = MFMA(a11, q1, s1a, 0, 0, 0);
            s0b = MFMA(b01, q1, s0b, 0, 0, 0);
            s1b = MFMA(b11, q1, s1b, 0, 0, 0);
            __builtin_amdgcn_s_setprio(0);
        }
        // max-free softmax (S already includes sc); truncation pack.
        float pa[8], pb[8];
        pa[0] = exp2f(s0a[0]); pa[1] = exp2f(s0a[1]);
        pa[2] = exp2f(s0a[2]); pa[3] = exp2f(s0a[3]);
        pa[4] = exp2f(s1a[0]); pa[5] = exp2f(s1a[1]);
        pa[6] = exp2f(s1a[2]); pa[7] = exp2f(s1a[3]);
        pb[0] = exp2f(s0b[0]); pb[1] = exp2f(s0b[1]);
        pb[2] = exp2f(s0b[2]); pb[3] = exp2f(s0b[3]);
        pb[4] = exp2f(s1b[0]); pb[5] = exp2f(s1b[1]);
        pb[6] = exp2f(s1b[2]); pb[7] = exp2f(s1b[3]);
        l_run += (((pa[0] + pa[1]) + (pa[2] + pa[3])) +
                  ((pa[4] + pa[5]) + (pa[6] + pa[7]))) +
                 (((pb[0] + pb[1]) + (pb[2] + pb[3])) +
                  ((pb[4] + pb[5]) + (pb[6] + pb[7])));
        s16x8 pha, phb;
        #pragma unroll
        for (int j = 0; j < 8; ++j) {
            pha[j] = (short)(__float_as_uint(pa[j]) >> 16);
            phb[j] = (short)(__float_as_uint(pb[j]) >> 16);
        }
        // PV: both halves accumulate into oacc
        __builtin_amdgcn_s_setprio(1);
        #pragma unroll
        for (int tt = 0; tt < 4; ++tt) {
            s16x8 vha = *(const s16x8*)&Vhs[cur][0][(tt * 16 + l15) * 36 + quad * 8];
            s16x8 vhb = *(const s16x8*)&Vhs[cur][1][(tt * 16 + l15) * 36 + quad * 8];
            oacc[tt] = MFMA(pha, vha, oacc[tt], 0, 0, 0);
            oacc[tt] = MFMA(phb, vhb, oacc[tt], 0, 0, 0);
        }
        __builtin_amdgcn_s_setprio(0);
        // stage tile t+1 into the other buffer
        if (t < 31) {
            u16* Kn = (u16*)Khs[cur ^ 1];
            *(u16x8*)&Kn[kr * 80 + kc] = kna;
            *(u16x8*)&Kn[(kr + 32) * 80 + kc] = knb;
            #pragma unroll
            for (int i = 0; i < 8; ++i) {
                Vhs[cur ^ 1][0][(vhd0 + i) * 36 + vslot] = vna[i];
                Vhs[cur ^ 1][1][(vhd0 + i) * 36 + vslot] = vnb[i];
            }
        }
    }

    // row-sum: combine the 4 quad groups (keys partitioned across quads)
    l_run += __shfl_xor(l_run, 16);
    l_run += __shfl_xor(l_run, 32);
    float linv[4];
    #pragma unroll
    for (int r = 0; r < 4; ++r)
        linv[r] = 1.f / fmaxf(__shfl(l_run, quad * 4 + r), 1e-35f);
    const long obase = ((long)orow_base + z * 2048 + qt * 64 + w * 16 + quad * 4) * 512 + h * 64;
    for (int tt = 0; tt < 4; ++tt)
        for (int r = 0; r < 4; ++r) {
            u16 hh, ll; split2(oacc[tt][r] * linv[r], hh, ll);
            const long oo = obase + (long)r * 512 + tt * 16 + l15;
            Oh[oo] = hh;
            Oh[olo + oo] = ll;
        }
}

// ---------------------------------------------------------------------------
// Residual + LayerNorm (D=512). a/b each either fp32 or hi/lo planes.
// Output fp32 and/or planes.
// ---------------------------------------------------------------------------
__global__ __launch_bounds__(256) void ln_p(
    const float* __restrict__ af, const u16* __restrict__ ah, long alo,
    const float* __restrict__ bf, const u16* __restrict__ bh, long blo,
    const float* __restrict__ g, const float* __restrict__ be,
    float* __restrict__ of, u16* __restrict__ oh, long olo)
{
    const int tid = threadIdx.x, lane = tid & 63, w = tid >> 6;
    const long base = ((long)blockIdx.x * 4 + w) * 512 + lane * 8;
    float v[8];
    if (af) {
        float4 f0 = *(const float4*)(af + base);
        float4 f1 = *(const float4*)(af + base + 4);
        v[0] = f0.x; v[1] = f0.y; v[2] = f0.z; v[3] = f0.w;
        v[4] = f1.x; v[5] = f1.y; v[6] = f1.z; v[7] = f1.w;
    } else {
        u16x8 hh = *(const u16x8*)(ah + base);
        u16x8 ll = *(const u16x8*)(ah + alo + base);
        for (int j = 0; j < 8; ++j) v[j] = bf2f(hh[j]) + bf2f(ll[j]);
    }
    if (bf) {
        float4 f0 = *(const float4*)(bf + base);
        float4 f1 = *(const float4*)(bf + base + 4);
        v[0] += f0.x; v[1] += f0.y; v[2] += f0.z; v[3] += f0.w;
        v[4] += f1.x; v[5] += f1.y; v[6] += f1.z; v[7] += f1.w;
    } else {
        u16x8 hh = *(const u16x8*)(bh + base);
        u16x8 ll = *(const u16x8*)(bh + blo + base);
        for (int j = 0; j < 8; ++j) v[j] += bf2f(hh[j]) + bf2f(ll[j]);
    }
    float s = 0.f, sq = 0.f;
    for (int j = 0; j < 8; ++j) { s += v[j]; sq += v[j] * v[j]; }
    for (int m = 1; m < 64; m <<= 1) { s += __shfl_xor(s, m); sq += __shfl_xor(sq, m); }
    const float mu = s * (1.f / 512.f);
    const float var = fmaxf(sq * (1.f / 512.f) - mu * mu, 0.f);
    const float rs = rsqrtf(var + 1e-5f);
    float4 ga = *(const float4*)(g + lane * 8);
    float4 gb = *(const float4*)(g + lane * 8 + 4);
    float4 ba = *(const float4*)(be + lane * 8);
    float4 bb = *(const float4*)(be + lane * 8 + 4);
    float gg[8] = {ga.x, ga.y, ga.z, ga.w, gb.x, gb.y, gb.z, gb.w};
    float bv[8] = {ba.x, ba.y, ba.z, ba.w, bb.x, bb.y, bb.z, bb.w};
    float o[8];
    for (int j = 0; j < 8; ++j) o[j] = (v[j] - mu) * rs * gg[j] + bv[j];
    if (of) {
        *(float4*)(of + base)     = make_float4(o[0], o[1], o[2], o[3]);
        *(float4*)(of + base + 4) = make_float4(o[4], o[5], o[6], o[7]);
    }
    if (oh) {
        u16x8 h8, l8;
        for (int j = 0; j < 8; ++j) { u16 hh, ll; split2(o[j], hh, ll); h8[j] = hh; l8[j] = ll; }
        *(u16x8*)(oh + base) = h8;
        *(u16x8*)(oh + olo + base) = l8;
    }
}

// Routing from hi/lo planes (argmax of logits). One wave per token.
// R11: no atomics -- counting moved into plan_k.
__global__ __launch_bounds__(256) void route_p(
    const u16* __restrict__ xh, long xlo,
    const float* __restrict__ gw, const float* __restrict__ gb,
    int* __restrict__ idx)
{
    const int tid = threadIdx.x, lane = tid & 63, w = tid >> 6;
    const long row = (long)blockIdx.x * 4 + w;
    const long base = row * 512 + lane * 8;
    u16x8 hh = *(const u16x8*)(xh + base);
    u16x8 ll = *(const u16x8*)(xh + xlo + base);
    float xf[8];
    for (int j = 0; j < 8; ++j) xf[j] = bf2f(hh[j]) + bf2f(ll[j]);
    float d0 = 0.f, d1 = 0.f, d2 = 0.f, d3 = 0.f;
    {
        float4 w0 = *(const float4*)(gw + 0 * 512 + lane * 8);
        float4 w1 = *(const float4*)(gw + 0 * 512 + lane * 8 + 4);
        float wf[8] = {w0.x, w0.y, w0.z, w0.w, w1.x, w1.y, w1.z, w1.w};
        for (int j = 0; j < 8; ++j) d0 += xf[j] * wf[j];
    }
    {
        float4 w0 = *(const float4*)(gw + 1 * 512 + lane * 8);
        float4 w1 = *(const float4*)(gw + 1 * 512 + lane * 8 + 4);
        float wf[8] = {w0.x, w0.y, w0.z, w0.w, w1.x, w1.y, w1.z, w1.w};
        for (int j = 0; j < 8; ++j) d1 += xf[j] * wf[j];
    }
    {
        float4 w0 = *(const float4*)(gw + 2 * 512 + lane * 8);
        float4 w1 = *(const float4*)(gw + 2 * 512 + lane * 8 + 4);
        float wf[8] = {w0.x, w0.y, w0.z, w0.w, w1.x, w1.y, w1.z, w1.w};
        for (int j = 0; j < 8; ++j) d2 += xf[j] * wf[j];
    }
    {
        float4 w0 = *(const float4*)(gw + 3 * 512 + lane * 8);
        float4 w1 = *(const float4*)(gw + 3 * 512 + lane * 8 + 4);
        float wf[8] = {w0.x, w0.y, w0.z, w0.w, w1.x, w1.y, w1.z, w1.w};
        for (int j = 0; j < 8; ++j) d3 += xf[j] * wf[j];
    }
    for (int m = 1; m < 64; m <<= 1) {
        d0 += __shfl_xor(d0, m);
        d1 += __shfl_xor(d1, m);
        d2 += __shfl_xor(d2, m);
        d3 += __shfl_xor(d3, m);
    }
    if (lane == 0) {
        d0 += gb[0]; d1 += gb[1]; d2 += gb[2]; d3 += gb[3];
        float best = d0; int bi = 0;
        if (d1 > best) { best = d1; bi = 1; }
        if (d2 > best) { best = d2; bi = 2; }
        if (d3 > best) { best = d3; bi = 3; }
        idx[row] = bi;
    }
}

// Count idx + lay out expert regions. Single wave: 64 threads x 128
// coalesced reads, register histogram, shuffle reduce, thread-0 plan.
__global__ void plan_k(const int* __restrict__ idx, int* __restrict__ cursors,
                       int* __restrict__ tile_expert)
{
    int c0 = 0, c1 = 0, c2 = 0, c3 = 0;
    for (int i = threadIdx.x; i < 8192; i += 64) {
        const int e = idx[i];
        c0 += (e == 0); c1 += (e == 1); c2 += (e == 2); c3 += (e == 3);
    }
    for (int m = 1; m < 64; m <<= 1) {
        c0 += __shfl_xor(c0, m);
        c1 += __shfl_xor(c1, m);
        c2 += __shfl_xor(c2, m);
        c3 += __shfl_xor(c3, m);
    }
    if (threadIdx.x == 0) {
        int counts[4] = {c0, c1, c2, c3};
        int off = 0;
        for (int e = 0; e < 4; ++e) {
            cursors[e] = off;
            int nt = (counts[e] + 63) >> 6;
            int t0 = off >> 6;
            for (int i = 0; i < nt; ++i) tile_expert[t0 + i] = e;
            off += nt << 6;
        }
        for (int t = off >> 6; t < 132; ++t) tile_expert[t] = -1;
    }
}

// Scatter: per-block LDS histogram gives local rank; ONE global atomic per
// block per expert (128 total). Any within-expert order is a valid
// permutation (gather/scatter use same perm).
__global__ __launch_bounds__(256) void scatter_k(
    const int* __restrict__ idx, int* __restrict__ cursors, int* __restrict__ perm)
{
    __shared__ int lcnt[4];
    __shared__ int lbase[4];
    const int t = blockIdx.x * 256 + threadIdx.x;
    if (threadIdx.x < 4) lcnt[threadIdx.x] = 0;
    __syncthreads();
    const int e = idx[t];
    const int lr = atomicAdd(&lcnt[e], 1);   // LDS atomic: local rank
    __syncthreads();
    if (threadIdx.x < 4)
        lbase[threadIdx.x] = atomicAdd(&cursors[threadIdx.x], lcnt[threadIdx.x]);
    __syncthreads();
    perm[lbase[e] + lr] = t;
}

// ===========================================================================
// R15: PROVEN R5/R13 memory layout (unchanged offsets, unchanged dataflow,
// no new overlaps) + the z=4 attention merge only. hi-only QKV needs exactly
// 3 x 8192x512x2B = 25.17MB = the existing QKVp region at stride T=4194304
// elements, so full-row QKV GEMMs + a single z=4 attn dispatch fit without
// any repacking. (R14's repacked layout NaN'd: its H-tail aliased ymoe --
// a hazard the R5 layout provably lacks: H [25.2,59.8MB), ymoe [67.1,..).)
// ===========================================================================
extern "C" void kernel_launch(void* const* d_in, const int* in_sizes, int n_in,
                              void* d_out, int out_size, void* d_ws, size_t ws_size,
                              hipStream_t stream)
{
    (void)in_sizes; (void)n_in; (void)out_size; (void)ws_size;
    const float* x        = (const float*)d_in[0];
    const float* mem      = (const float*)d_in[1];
    const float* sa_in_w  = (const float*)d_in[2];
    const float* sa_in_b  = (const float*)d_in[3];
    const float* sa_out_w = (const float*)d_in[4];
    const float* sa_out_b = (const float*)d_in[5];
    const float* ca_in_w  = (const float*)d_in[6];
    const float* ca_in_b  = (const float*)d_in[7];
    const float* ca_out_w = (const float*)d_in[8];
    const float* ca_out_b = (const float*)d_in[9];
    const float* gate_w   = (const float*)d_in[10];
    const float* gate_b   = (const float*)d_in[11];
    const float* w1       = (const float*)d_in[12];
    const float* b1       = (const float*)d_in[13];
    const float* w2       = (const float*)d_in[14];
    const float* b2       = (const float*)d_in[15];
    const float* ln1_g    = (const float*)d_in[16];
    const float* ln1_b    = (const float*)d_in[17];
    const float* ln2_g    = (const float*)d_in[18];
    const float* ln2_b    = (const float*)d_in[19];
    const float* ln3_g    = (const float*)d_in[20];
    const float* ln3_b    = (const float*)d_in[21];

    const float sc = 0.125f * 1.4426950408889634f;
    dim3 blk(256, 1, 1);
    char* ws = (char*)d_ws;

    // attn weight plane offsets (elements within WA)
    const long WAe_sa_in = 0, WAe_sa_out = 1572864, WAe_ca_in = 2097152, WAe_ca_out = 3670016;

    // -------- proven R5/R13 layout --------
    u16* WA   = (u16*)(ws);
    u16* w1h  = (u16*)(ws + 8388608L);
    u16* w2h  = (u16*)(ws + 16777216L);
    u16* QKVp = (u16*)(ws + 25165824L);   // 3 hi-only tensors, stride T; MoE H later
    u16* Op   = (u16*)(ws + 50331648L);   // hi+lo, lo at +L_8K
    u16* P1p  = (u16*)(ws + 67108864L);   // hi+lo out-proj result
    float* ymoe = (float*)(ws + 67108864L);
    u16* X1p  = (u16*)(ws + 83886080L);   // hi+lo residual
    int* idx    = (int*)(ws + 100663296L);
    int* perm   = (int*)(ws + 100663296L + 32768);
    int* cursors= (int*)(ws + 100663296L + 32768 + 33792 + 16);
    int* tile_e = (int*)(ws + 100663296L + 32768 + 33792 + 32);

    const long T    = 4194304;   // QKV tensor stride (hi-only), elements
    const long L_8K = 4194304;   // lo-plane offset for hi+lo tensors, elements
    const long SL   = 1048576;
    (void)SL;

    hipMemsetAsync(perm, 0xFF, 8448 * 4, stream);

    split_k<<<dim3(384), blk, 0, stream>>>(sa_in_w,  WA + WAe_sa_in,  WA + WAe_sa_in + 786432, 786432);
    split_k<<<dim3(128), blk, 0, stream>>>(sa_out_w, WA + WAe_sa_out, WA + WAe_sa_out + 262144, 262144);
    split_k<<<dim3(384), blk, 0, stream>>>(ca_in_w,  WA + WAe_ca_in,  WA + WAe_ca_in + 786432, 786432);
    split_k<<<dim3(128), blk, 0, stream>>>(ca_out_w, WA + WAe_ca_out, WA + WAe_ca_out + 262144, 262144);
    splitT_k<<<dim3(32, 8, 4), blk, 0, stream>>>(w1, w1h, 512, 2048);
    splitT_k<<<dim3(8, 32, 4), blk, 0, stream>>>(w2, w2h, 2048, 512);

    // ---- self attention: full-row QKV (1-term) + single z=4 attn ----
    gemm_s<<<dim3(128, 24), blk, 0, stream>>>(
        x, nullptr, nullptr, 512, 0, nullptr,
        WA + WAe_sa_in, nullptr, 512, 0, nullptr,
        sa_in_b, 0, nullptr, 0, nullptr,
        QKVp, 0, 512, 9, T, 512, 0);
    attn_p<<<dim3(32, 8, 4), blk, 0, stream>>>(
        QKVp, QKVp + T, QKVp + 2 * T, 0, Op, L_8K, 0, sc);
    gemm_s<<<dim3(128, 8), blk, 0, stream>>>(
        nullptr, Op, Op + L_8K, 512, 1, nullptr,
        WA + WAe_sa_out, WA + WAe_sa_out + 262144, 512, 0, nullptr,
        sa_out_b, 0, nullptr, 0, nullptr,
        P1p, L_8K, 512, 9, 0, 512, 0);
    ln_p<<<dim3(2048), blk, 0, stream>>>(x, nullptr, 0, nullptr, P1p, L_8K,
                                         ln1_g, ln1_b, nullptr, X1p, L_8K);

    // ---- cross attention ----
    gemm_s<<<dim3(128, 8), blk, 0, stream>>>(
        nullptr, X1p, nullptr, 512, 0, nullptr,
        WA + WAe_ca_in, nullptr, 512, 0, nullptr,
        ca_in_b, 0, nullptr, 0, nullptr,
        QKVp, 0, 512, 9, T, 512, 0);                    // Q -> tensor 0
    gemm_s<<<dim3(128, 16), blk, 0, stream>>>(
        mem, nullptr, nullptr, 512, 0, nullptr,
        WA + WAe_ca_in + 262144, nullptr, 512, 0, nullptr,
        ca_in_b + 512, 0, nullptr, 0, nullptr,
        QKVp + T, 0, 512, 9, T, 512, 0);                // K,V -> tensors 1,2
    attn_p<<<dim3(32, 8, 4), blk, 0, stream>>>(
        QKVp, QKVp + T, QKVp + 2 * T, 0, Op, L_8K, 0, sc);
    gemm_s<<<dim3(128, 8), blk, 0, stream>>>(
        nullptr, Op, Op + L_8K, 512, 1, nullptr,
        WA + WAe_ca_out, WA + WAe_ca_out + 262144, 512, 0, nullptr,
        ca_out_b, 0, nullptr, 0, nullptr,
        P1p, L_8K, 512, 9, 0, 512, 0);
    ln_p<<<dim3(2048), blk, 0, stream>>>(nullptr, X1p, L_8K, nullptr, P1p, L_8K,
                                         ln2_g, ln2_b, nullptr, X1p, L_8K);

    // ---- MoE (top-1, grouped; proven 2x66-tile chunking, H in QKVp) ----
    route_p<<<dim3(2048), blk, 0, stream>>>(X1p, L_8K, gate_w, gate_b, idx);
    plan_k<<<dim3(1), dim3(64), 0, stream>>>(idx, cursors, tile_e);
    scatter_k<<<dim3(32), blk, 0, stream>>>(idx, cursors, perm);
    for (int c = 0; c < 2; ++c) {
        const int t0 = c * 66;
        gemm_s<<<dim3(66, 32), blk, 0, stream>>>(
            nullptr, X1p, nullptr, 512, 0, perm + t0 * 64,
            w1h, nullptr, 512, 1048576, tile_e + t0,
            b1, 2048, nullptr, 0, nullptr,
            QKVp, 0, 2048, 31, 0, 512, 1);
        gemm_s<<<dim3(66, 8), blk, 0, stream>>>(
            nullptr, QKVp, nullptr, 2048, 0, nullptr,
            w2h, nullptr, 2048, 1048576, tile_e + t0,
            b2, 512, ymoe, 512, perm + t0 * 64,
            nullptr, 0, 0, 31, 0, 2048, 0);
    }
    ln_p<<<dim3(2048), blk, 0, stream>>>(nullptr, X1p, L_8K, ymoe, nullptr, 0,
                                         ln3_g, ln3_b, (float*)d_out, nullptr, 0);
}

// Round 12
// 654.773 us; speedup vs baseline: 1.0635x; 1.0635x over previous
//
#include <hip/hip_runtime.h>

typedef unsigned short u16;
typedef __attribute__((ext_vector_type(8))) short s16x8;
typedef __attribute__((ext_vector_type(8))) unsigned short u16x8;
typedef __attribute__((ext_vector_type(4))) unsigned short u16x4;
typedef __attribute__((ext_vector_type(4))) float f32x4;

#define DEV static __device__ __forceinline__
#define MFMA __builtin_amdgcn_mfma_f32_16x16x32_bf16

DEV float bf2f(u16 u) { return __uint_as_float(((unsigned)u) << 16); }
DEV u16 f2bf(float f) {
    unsigned u = __float_as_uint(f);
    return (u16)((u + 0x7FFFu + ((u >> 16) & 1u)) >> 16);
}
DEV void split2(float v, u16& hi, u16& lo) {
    hi = f2bf(v);
    lo = f2bf(v - bf2f(hi));
}

// ===========================================================================
// bf16 hi/lo plane pipeline kernels (verified R5/R13)
// ===========================================================================

// Split fp32 -> bf16 hi/lo planes, elementwise. n multiple of 2048.
__global__ __launch_bounds__(256) void split_k(
    const float* __restrict__ src, u16* __restrict__ dh, u16* __restrict__ dl, long n)
{
    const long i = ((long)blockIdx.x * 256 + threadIdx.x) * 8;
    if (i >= n) return;
    float4 f0 = *(const float4*)(src + i);
    float4 f1 = *(const float4*)(src + i + 4);
    float v[8] = {f0.x, f0.y, f0.z, f0.w, f1.x, f1.y, f1.z, f1.w};
    u16x8 h8, l8;
    for (int j = 0; j < 8; ++j) { u16 hh, ll; split2(v[j], hh, ll); h8[j] = hh; l8[j] = ll; }
    *(u16x8*)(dh + i) = h8;
    *(u16x8*)(dl + i) = l8;
}

// Transpose+split (hi only): src [E][K][N] fp32 -> dst [E][N][K] bf16.
__global__ __launch_bounds__(256) void splitT_k(
    const float* __restrict__ src, u16* __restrict__ dst, int K, int N)
{
    __shared__ u16 tile[64 * 72];
    const int e = blockIdx.z;
    const int n0 = blockIdx.x * 64, k0 = blockIdx.y * 64;
    const long estride = (long)K * N;
    const int tid = threadIdx.x;
    const int tr = tid >> 2, tc = (tid & 3) * 16;
    {
        const float* sp = src + e * estride + (long)(k0 + tr) * N + n0 + tc;
        for (int j = 0; j < 16; j += 4) {
            float4 f = *(const float4*)(sp + j);
            tile[tr * 72 + tc + j + 0] = f2bf(f.x);
            tile[tr * 72 + tc + j + 1] = f2bf(f.y);
            tile[tr * 72 + tc + j + 2] = f2bf(f.z);
            tile[tr * 72 + tc + j + 3] = f2bf(f.w);
        }
    }
    __syncthreads();
    {
        const int tn = tid >> 2, tk = (tid & 3) * 16;
        u16* dp = dst + e * estride + (long)(n0 + tn) * K + k0 + tk;
        u16x8 o0, o1;
        for (int j = 0; j < 8; ++j) {
            o0[j] = tile[(tk + j) * 72 + tn];
            o1[j] = tile[(tk + 8 + j) * 72 + tn];
        }
        *(u16x8*)(dp) = o0;
        *(u16x8*)(dp + 8) = o1;
    }
}

// ---------------------------------------------------------------------------
// gemm1_s: 1-term bf16 GEMM, double-buffered LDS, ONE barrier per k-step
// (attn-R9 proven pattern: top-of-iter barrier covers both "buf[cur] staged"
// and "buf[cur^1] readers done"; next tile's global loads are issued before
// compute so they stay in flight across the barrier). LDS 2x(As+Bs) =
// 18.4 KB = same footprint as the old 4-array gemm_s -> occupancy ceiling
// unchanged. A: fp32 (converted to hi at staging) or bf16 hi plane.
// C: fp32 (perm_out scatter) and/or hi plane (tensor routing via ts).
// ---------------------------------------------------------------------------
__global__ __launch_bounds__(256) void gemm1_s(
    const float* __restrict__ Af, const u16* __restrict__ Ahp,
    int lda, const int* __restrict__ perm_in,
    const u16* __restrict__ Bh, int ldb, long b_estride,
    const int* __restrict__ tile_expert,
    const float* __restrict__ bias, int bias_estride,
    float* __restrict__ Cf, int ldcf, const int* __restrict__ perm_out,
    u16* __restrict__ Ch, int ldcp, int ts, long tstride,
    int K, int act)
{
    __shared__ u16 As[2][64 * 36], Bs[2][64 * 36];
    const int mt = blockIdx.x, nt = blockIdx.y;
    int e = 0;
    if (tile_expert) { e = tile_expert[mt]; if (e < 0) return; }
    const int tid = threadIdx.x, lane = tid & 63, w = tid >> 6;
    const int wr = (w >> 1) * 32, wc = (w & 1) * 32;
    const int quad = lane >> 4, l15 = lane & 15;

    const u16* Bhb = Bh + (long)e * b_estride;

    const int r2 = tid >> 3, c4 = (tid & 7) * 4;   // fp32-A staging
    const int r1 = tid >> 2, c8 = (tid & 3) * 8;   // plane staging
    long arow0 = 0, arow1 = 0, arowb = 0;
    bool v0 = true, v1 = true, vb = true;
    if (perm_in) {
        if (Af) {
            int p0 = perm_in[mt * 64 + r2];      v0 = p0 >= 0; arow0 = p0 < 0 ? 0 : p0;
            int p1 = perm_in[mt * 64 + r2 + 32]; v1 = p1 >= 0; arow1 = p1 < 0 ? 0 : p1;
        } else {
            int pb = perm_in[mt * 64 + r1];      vb = pb >= 0; arowb = pb < 0 ? 0 : pb;
        }
    } else {
        arow0 = (long)mt * 64 + r2; arow1 = arow0 + 32; arowb = (long)mt * 64 + r1;
    }

    f32x4 acc[2][2] = {};
    const int NT = K >> 5;

    u16x8 ra, rb;
    float4 fa0, fa1;

    // load + stage tile 0 into buf 0
    if (Af) {
        fa0 = v0 ? *(const float4*)(Af + arow0 * (long)lda + c4) : make_float4(0.f, 0.f, 0.f, 0.f);
        fa1 = v1 ? *(const float4*)(Af + arow1 * (long)lda + c4) : make_float4(0.f, 0.f, 0.f, 0.f);
    } else {
        ra = vb ? *(const u16x8*)(Ahp + arowb * (long)lda + c8) : (u16x8)(u16)0;
    }
    rb = *(const u16x8*)(Bhb + ((long)nt * 64 + r1) * ldb + c8);
    if (Af) {
        u16x4 h4;
        float t0a[4] = {fa0.x, fa0.y, fa0.z, fa0.w};
        for (int i = 0; i < 4; ++i) h4[i] = f2bf(t0a[i]);
        *(u16x4*)&As[0][r2 * 36 + c4] = h4;
        float t0b[4] = {fa1.x, fa1.y, fa1.z, fa1.w};
        for (int i = 0; i < 4; ++i) h4[i] = f2bf(t0b[i]);
        *(u16x4*)&As[0][(32 + r2) * 36 + c4] = h4;
    } else {
        *(u16x8*)&As[0][r1 * 36 + c8] = ra;
    }
    *(u16x8*)&Bs[0][r1 * 36 + c8] = rb;

    for (int t = 0; t < NT; ++t) {
        const int cur = t & 1;
        __syncthreads();   // buf[cur] staged; buf[cur^1] readers (iter t-1) done
        if (t + 1 < NT) {  // issue next tile's loads (in flight across compute)
            const int k0 = (t + 1) * 32;
            if (Af) {
                fa0 = v0 ? *(const float4*)(Af + arow0 * (long)lda + k0 + c4) : make_float4(0.f, 0.f, 0.f, 0.f);
                fa1 = v1 ? *(const float4*)(Af + arow1 * (long)lda + k0 + c4) : make_float4(0.f, 0.f, 0.f, 0.f);
            } else {
                ra = vb ? *(const u16x8*)(Ahp + arowb * (long)lda + k0 + c8) : (u16x8)(u16)0;
            }
            rb = *(const u16x8*)(Bhb + ((long)nt * 64 + r1) * ldb + k0 + c8);
        }
        {
            s16x8 ah0 = *(const s16x8*)&As[cur][(wr + l15) * 36 + quad * 8];
            s16x8 ah1 = *(const s16x8*)&As[cur][(wr + 16 + l15) * 36 + quad * 8];
            s16x8 bh0 = *(const s16x8*)&Bs[cur][(wc + l15) * 36 + quad * 8];
            s16x8 bh1 = *(const s16x8*)&Bs[cur][(wc + 16 + l15) * 36 + quad * 8];
            __builtin_amdgcn_s_setprio(1);
            acc[0][0] = MFMA(ah0, bh0, acc[0][0], 0, 0, 0);
            acc[0][1] = MFMA(ah0, bh1, acc[0][1], 0, 0, 0);
            acc[1][0] = MFMA(ah1, bh0, acc[1][0], 0, 0, 0);
            acc[1][1] = MFMA(ah1, bh1, acc[1][1], 0, 0, 0);
            __builtin_amdgcn_s_setprio(0);
        }
        if (t + 1 < NT) {   // stage next tile into the other buffer
            const int nx = cur ^ 1;
            if (Af) {
                u16x4 h4;
                float tna[4] = {fa0.x, fa0.y, fa0.z, fa0.w};
                for (int i = 0; i < 4; ++i) h4[i] = f2bf(tna[i]);
                *(u16x4*)&As[nx][r2 * 36 + c4] = h4;
                float tnb[4] = {fa1.x, fa1.y, fa1.z, fa1.w};
                for (int i = 0; i < 4; ++i) h4[i] = f2bf(tnb[i]);
                *(u16x4*)&As[nx][(32 + r2) * 36 + c4] = h4;
            } else {
                *(u16x8*)&As[nx][r1 * 36 + c8] = ra;
            }
            *(u16x8*)&Bs[nx][r1 * 36 + c8] = rb;
        }
    }

    const float* bp = bias + (long)e * bias_estride;
    for (int mi = 0; mi < 2; ++mi) {
        for (int r = 0; r < 4; ++r) {
            const int rloc = wr + mi * 16 + quad * 4 + r;  // C/D: row=(lane>>4)*4+reg
            const long lrow = (long)mt * 64 + rloc;
            for (int ni = 0; ni < 2; ++ni) {
                const int colg = nt * 64 + wc + ni * 16 + l15;  // C/D: col=lane&15
                float v = acc[mi][ni][r] + bp[colg];
                if (act == 1) v = 0.5f * v * (1.f + erff(v * 0.7071067811865475f));
                if (Cf) {
                    long orow = lrow;
                    if (perm_out) { int po = perm_out[mt * 64 + rloc]; if (po < 0) continue; orow = po; }
                    Cf[orow * (long)ldcf + colg] = v;
                }
                if (Ch) {
                    const int tq = colg >> ts;
                    const int cc = colg - (tq << ts);
                    Ch[(long)tq * tstride + lrow * (long)ldcp + cc] = f2bf(v);
                }
            }
        }
    }
}

// ---------------------------------------------------------------------------
// GEMM (plane pipeline, 3-term): C = act(A @ B^T + bias). Retained for the
// two out-projections (hi+lo A and B). R13 LDS stride 36 (conflict-free).
// ---------------------------------------------------------------------------
__global__ __launch_bounds__(256) void gemm_s(
    const float* __restrict__ Af, const u16* __restrict__ Ahp, const u16* __restrict__ Alp,
    int lda, int a_lo, const int* __restrict__ perm_in,
    const u16* __restrict__ Bh, const u16* __restrict__ Bl, int ldb, long b_estride,
    const int* __restrict__ tile_expert,
    const float* __restrict__ bias, int bias_estride,
    float* __restrict__ Cf, int ldcf, const int* __restrict__ perm_out,
    u16* __restrict__ Ch, long clo_off, int ldcp, int ts, long tstride,
    int K, int act)
{
    __shared__ u16 As[64 * 36], Als[64 * 36];
    __shared__ u16 Bs[64 * 36], Bls[64 * 36];
    const int mt = blockIdx.x, nt = blockIdx.y;
    int e = 0;
    if (tile_expert) { e = tile_expert[mt]; if (e < 0) return; }
    const int tid = threadIdx.x, lane = tid & 63, w = tid >> 6;
    const int wr = (w >> 1) * 32, wc = (w & 1) * 32;
    const int quad = lane >> 4, l15 = lane & 15;
    const int b_lo = (Bl != nullptr);

    const u16* Bhb = Bh + (long)e * b_estride;
    const u16* Blb = b_lo ? (Bl + (long)e * b_estride) : nullptr;

    const int r2 = tid >> 3, c4 = (tid & 7) * 4;   // fp32-A staging
    const int r1 = tid >> 2, c8 = (tid & 3) * 8;   // plane staging
    long arow0 = 0, arow1 = 0, arowb = 0;
    bool v0 = true, v1 = true, vb = true;
    if (perm_in) {
        if (Af) {
            int p0 = perm_in[mt * 64 + r2];      v0 = p0 >= 0; arow0 = p0 < 0 ? 0 : p0;
            int p1 = perm_in[mt * 64 + r2 + 32]; v1 = p1 >= 0; arow1 = p1 < 0 ? 0 : p1;
        } else {
            int pb = perm_in[mt * 64 + r1];      vb = pb >= 0; arowb = pb < 0 ? 0 : pb;
        }
    } else {
        arow0 = (long)mt * 64 + r2; arow1 = arow0 + 32; arowb = (long)mt * 64 + r1;
    }

    f32x4 acc[2][2] = {};

    for (int k0 = 0; k0 < K; k0 += 32) {
        __syncthreads();
        if (Af) {
            for (int half = 0; half < 2; ++half) {
                const int row = half * 32 + r2;
                const long ar = half ? arow1 : arow0;
                const bool va = half ? v1 : v0;
                float4 v = va ? *(const float4*)(Af + ar * (long)lda + k0 + c4)
                              : make_float4(0.f, 0.f, 0.f, 0.f);
                float vv[4] = {v.x, v.y, v.z, v.w};
                u16x4 h4, l4;
                for (int i = 0; i < 4; ++i) { u16 hh, ll; split2(vv[i], hh, ll); h4[i] = hh; l4[i] = ll; }
                *(u16x4*)&As[row * 36 + c4] = h4;
                if (a_lo) *(u16x4*)&Als[row * 36 + c4] = l4;
            }
        } else {
            const long ao = arowb * (long)lda + k0 + c8;
            u16x8 h8 = vb ? *(const u16x8*)(Ahp + ao) : (u16x8)(u16)0;
            *(u16x8*)&As[r1 * 36 + c8] = h8;
            if (a_lo) {
                u16x8 l8 = vb ? *(const u16x8*)(Alp + ao) : (u16x8)(u16)0;
                *(u16x8*)&Als[r1 * 36 + c8] = l8;
            }
        }
        {
            const long bo = ((long)nt * 64 + r1) * ldb + k0 + c8;
            *(u16x8*)&Bs[r1 * 36 + c8] = *(const u16x8*)(Bhb + bo);
            if (b_lo) *(u16x8*)&Bls[r1 * 36 + c8] = *(const u16x8*)(Blb + bo);
        }
        __syncthreads();
        s16x8 ah0 = *(const s16x8*)&As[(wr + l15) * 36 + quad * 8];
        s16x8 ah1 = *(const s16x8*)&As[(wr + 16 + l15) * 36 + quad * 8];
        s16x8 bh0 = *(const s16x8*)&Bs[(wc + l15) * 36 + quad * 8];
        s16x8 bh1 = *(const s16x8*)&Bs[(wc + 16 + l15) * 36 + quad * 8];
        acc[0][0] = MFMA(ah0, bh0, acc[0][0], 0, 0, 0);
        acc[0][1] = MFMA(ah0, bh1, acc[0][1], 0, 0, 0);
        acc[1][0] = MFMA(ah1, bh0, acc[1][0], 0, 0, 0);
        acc[1][1] = MFMA(ah1, bh1, acc[1][1], 0, 0, 0);
        if (a_lo) {
            s16x8 al0 = *(const s16x8*)&Als[(wr + l15) * 36 + quad * 8];
            s16x8 al1 = *(const s16x8*)&Als[(wr + 16 + l15) * 36 + quad * 8];
            acc[0][0] = MFMA(al0, bh0, acc[0][0], 0, 0, 0);
            acc[0][1] = MFMA(al0, bh1, acc[0][1], 0, 0, 0);
            acc[1][0] = MFMA(al1, bh0, acc[1][0], 0, 0, 0);
            acc[1][1] = MFMA(al1, bh1, acc[1][1], 0, 0, 0);
        }
        if (b_lo) {
            s16x8 bl0 = *(const s16x8*)&Bls[(wc + l15) * 36 + quad * 8];
            s16x8 bl1 = *(const s16x8*)&Bls[(wc + 16 + l15) * 36 + quad * 8];
            acc[0][0] = MFMA(ah0, bl0, acc[0][0], 0, 0, 0);
            acc[0][1] = MFMA(ah0, bl1, acc[0][1], 0, 0, 0);
            acc[1][0] = MFMA(ah1, bl0, acc[1][0], 0, 0, 0);
            acc[1][1] = MFMA(ah1, bl1, acc[1][1], 0, 0, 0);
        }
    }

    const float* bp = bias + (long)e * bias_estride;
    for (int mi = 0; mi < 2; ++mi) {
        for (int r = 0; r < 4; ++r) {
            const int rloc = wr + mi * 16 + quad * 4 + r;  // C/D: row=(lane>>4)*4+reg
            const long lrow = (long)mt * 64 + rloc;
            for (int ni = 0; ni < 2; ++ni) {
                const int colg = nt * 64 + wc + ni * 16 + l15;  // C/D: col=lane&15
                float v = acc[mi][ni][r] + bp[colg];
                if (act == 1) v = 0.5f * v * (1.f + erff(v * 0.7071067811865475f));
                if (Cf) {
                    long orow = lrow;
                    if (perm_out) { int po = perm_out[mt * 64 + rloc]; if (po < 0) continue; orow = po; }
                    Cf[orow * (long)ldcf + colg] = v;
                }
                if (Ch) {
                    const int t = colg >> ts;
                    const int cc = colg - (t << ts);
                    const long po = (long)t * tstride + lrow * (long)ldcp + cc;
                    u16 hh, ll; split2(v, hh, ll);
                    Ch[po] = hh;
                    if (clo_off) Ch[po + clo_off] = ll;
                }
            }
        }
    }
}

// ---------------------------------------------------------------------------
// Flash attention, single-plane bf16 (R12/R13 verified; z=4 launch).
// ---------------------------------------------------------------------------
__global__ __launch_bounds__(256) void attn_p(
    const u16* __restrict__ Qh, const u16* __restrict__ Kh, const u16* __restrict__ Vh,
    long plo, u16* __restrict__ Oh, long olo, int orow_base, float sc)
{
    (void)plo;
    __shared__ u16 Khs[2][64 * 80];     // [buf][64 keys x 64 dims]
    __shared__ u16 Vhs[2][2][64 * 36];  // [buf][key-half][64 dims x 32 slots]
    // XCD swizzle: cluster the 32 qt blocks of one (z,h) onto one XCD.
    const int Z = gridDim.z;
    const int lin = blockIdx.x + 32 * (blockIdx.y + 8 * blockIdx.z);
    const int g = lin & 7, li = lin >> 3;
    const int p = g * Z + (li >> 5);
    const int qt = li & 31;
    const int h = p & 7, z = p >> 3;

    const int tid = threadIdx.x, lane = tid & 63, w = tid >> 6;
    const int quad = lane >> 4, l15 = lane & 15;

    // Q fragment (B-operand of swapped QK^T), pre-scaled by sc.
    const long qoff = ((long)z * 2048 + qt * 64 + w * 16 + l15) * 512 + h * 64 + quad * 8;
    s16x8 q0, q1;
    {
        s16x8 q0r = *(const s16x8*)(Qh + qoff);
        s16x8 q1r = *(const s16x8*)(Qh + qoff + 32);
        #pragma unroll
        for (int j = 0; j < 8; ++j) {
            q0[j] = (short)f2bf(bf2f((u16)q0r[j]) * sc);
            q1[j] = (short)f2bf(bf2f((u16)q1r[j]) * sc);
        }
    }

    const int kr = tid >> 3, kc = (tid & 7) * 8;       // K stage: rows kr, kr+32
    const int vkey = tid & 31, vhd0 = (tid >> 5) * 8;  // V stage: keys vkey, vkey+32
    // PV A-frag keyslot(quad,j) = quad*4+(j&3)+16*(j>>2); sigma = inverse (R9).
    const int vslot = ((vkey >> 2) & 3) * 8 + (vkey & 3) + ((vkey >> 4) << 2);
    const long kbase = ((long)z * 2048 + kr) * 512 + h * 64 + kc;
    const long vbase = ((long)z * 2048 + vkey) * 512 + h * 64 + vhd0;

    // prologue: stage tile 0 (keys 0..63) into buffer 0
    {
        u16x8 ka = *(const u16x8*)(Kh + kbase);
        u16x8 kb = *(const u16x8*)(Kh + kbase + 32L * 512);
        u16x8 va = *(const u16x8*)(Vh + vbase);
        u16x8 vb = *(const u16x8*)(Vh + vbase + 32L * 512);
        *(u16x8*)&Khs[0][kr * 80 + kc] = ka;
        *(u16x8*)&Khs[0][(kr + 32) * 80 + kc] = kb;
        #pragma unroll
        for (int i = 0; i < 8; ++i) {
            Vhs[0][0][(vhd0 + i) * 36 + vslot] = va[i];
            Vhs[0][1][(vhd0 + i) * 36 + vslot] = vb[i];
        }
    }

    float l_run = 0.f;
    f32x4 oacc[4] = {};

    for (int t = 0; t < 32; ++t) {
        const int cur = t & 1;
        __syncthreads();   // buf[cur] staged & visible
        u16x8 kna, knb, vna, vnb;
        if (t < 31) {
            const long o = (long)(t + 1) * 32768;   // 64 keys * 512 dims
            kna = *(const u16x8*)(Kh + kbase + o);
            knb = *(const u16x8*)(Kh + kbase + 32L * 512 + o);
            vna = *(const u16x8*)(Vh + vbase + o);
            vnb = *(const u16x8*)(Vh + vbase + 32L * 512 + o);
        }
        const u16* Kc = Khs[cur];
        // ---- two independent 32-key chains ----
        f32x4 s0a = {0.f, 0.f, 0.f, 0.f}, s1a = {0.f, 0.f, 0.f, 0.f};
        f32x4 s0b = {0.f, 0.f, 0.f, 0.f}, s1b = {0.f, 0.f, 0.f, 0.f};
        {
            s16x8 a00 = *(const s16x8*)&Kc[l15 * 80 + quad * 8];
            s16x8 a01 = *(const s16x8*)&Kc[l15 * 80 + 32 + quad * 8];
            s16x8 a10 = *(const s16x8*)&Kc[(16 + l15) * 80 + quad * 8];
            s16x8 a11 = *(const s16x8*)&Kc[(16 + l15) * 80 + 32 + quad * 8];
            s16x8 b00 = *(const s16x8*)&Kc[(32 + l15) * 80 + quad * 8];
            s16x8 b01 = *(const s16x8*)&Kc[(32 + l15) * 80 + 32 + quad * 8];
            s16x8 b10 = *(const s16x8*)&Kc[(48 + l15) * 80 + quad * 8];
            s16x8 b11 = *(const s16x8*)&Kc[(48 + l15) * 80 + 32 + quad * 8];
            __builtin_amdgcn_s_setprio(1);
            s0a = MFMA(a00, q0, s0a, 0, 0, 0);
            s1a = MFMA(a10, q0, s1a, 0, 0, 0);
            s0b = MFMA(b00, q0, s0b, 0, 0, 0);
            s1b = MFMA(b10, q0, s1b, 0, 0, 0);
            s0a = MFMA(a01, q1, s0a, 0, 0, 0);
            s1a = MFMA(a11, q1, s1a, 0, 0, 0);
            s0b = MFMA(b01, q1, s0b, 0, 0, 0);
            s1b = MFMA(b11, q1, s1b, 0, 0, 0);
            __builtin_amdgcn_s_setprio(0);
        }
        // max-free softmax (S already includes sc); truncation pack.
        float pa[8], pb[8];
        pa[0] = exp2f(s0a[0]); pa[1] = exp2f(s0a[1]);
        pa[2] = exp2f(s0a[2]); pa[3] = exp2f(s0a[3]);
        pa[4] = exp2f(s1a[0]); pa[5] = exp2f(s1a[1]);
        pa[6] = exp2f(s1a[2]); pa[7] = exp2f(s1a[3]);
        pb[0] = exp2f(s0b[0]); pb[1] = exp2f(s0b[1]);
        pb[2] = exp2f(s0b[2]); pb[3] = exp2f(s0b[3]);
        pb[4] = exp2f(s1b[0]); pb[5] = exp2f(s1b[1]);
        pb[6] = exp2f(s1b[2]); pb[7] = exp2f(s1b[3]);
        l_run += (((pa[0] + pa[1]) + (pa[2] + pa[3])) +
                  ((pa[4] + pa[5]) + (pa[6] + pa[7]))) +
                 (((pb[0] + pb[1]) + (pb[2] + pb[3])) +
                  ((pb[4] + pb[5]) + (pb[6] + pb[7])));
        s16x8 pha, phb;
        #pragma unroll
        for (int j = 0; j < 8; ++j) {
            pha[j] = (short)(__float_as_uint(pa[j]) >> 16);
            phb[j] = (short)(__float_as_uint(pb[j]) >> 16);
        }
        // PV: both halves accumulate into oacc
        __builtin_amdgcn_s_setprio(1);
        #pragma unroll
        for (int tt = 0; tt < 4; ++tt) {
            s16x8 vha = *(const s16x8*)&Vhs[cur][0][(tt * 16 + l15) * 36 + quad * 8];
            s16x8 vhb = *(const s16x8*)&Vhs[cur][1][(tt * 16 + l15) * 36 + quad * 8];
            oacc[tt] = MFMA(pha, vha, oacc[tt], 0, 0, 0);
            oacc[tt] = MFMA(phb, vhb, oacc[tt], 0, 0, 0);
        }
        __builtin_amdgcn_s_setprio(0);
        // stage tile t+1 into the other buffer
        if (t < 31) {
            u16* Kn = (u16*)Khs[cur ^ 1];
            *(u16x8*)&Kn[kr * 80 + kc] = kna;
            *(u16x8*)&Kn[(kr + 32) * 80 + kc] = knb;
            #pragma unroll
            for (int i = 0; i < 8; ++i) {
                Vhs[cur ^ 1][0][(vhd0 + i) * 36 + vslot] = vna[i];
                Vhs[cur ^ 1][1][(vhd0 + i) * 36 + vslot] = vnb[i];
            }
        }
    }

    // row-sum: combine the 4 quad groups (keys partitioned across quads)
    l_run += __shfl_xor(l_run, 16);
    l_run += __shfl_xor(l_run, 32);
    float linv[4];
    #pragma unroll
    for (int r = 0; r < 4; ++r)
        linv[r] = 1.f / fmaxf(__shfl(l_run, quad * 4 + r), 1e-35f);
    const long obase = ((long)orow_base + z * 2048 + qt * 64 + w * 16 + quad * 4) * 512 + h * 64;
    for (int tt = 0; tt < 4; ++tt)
        for (int r = 0; r < 4; ++r) {
            u16 hh, ll; split2(oacc[tt][r] * linv[r], hh, ll);
            const long oo = obase + (long)r * 512 + tt * 16 + l15;
            Oh[oo] = hh;
            Oh[olo + oo] = ll;
        }
}

// ---------------------------------------------------------------------------
// Residual + LayerNorm (D=512). a/b each either fp32 or hi/lo planes.
// Output fp32 and/or planes.
// ---------------------------------------------------------------------------
__global__ __launch_bounds__(256) void ln_p(
    const float* __restrict__ af, const u16* __restrict__ ah, long alo,
    const float* __restrict__ bf, const u16* __restrict__ bh, long blo,
    const float* __restrict__ g, const float* __restrict__ be,
    float* __restrict__ of, u16* __restrict__ oh, long olo)
{
    const int tid = threadIdx.x, lane = tid & 63, w = tid >> 6;
    const long base = ((long)blockIdx.x * 4 + w) * 512 + lane * 8;
    float v[8];
    if (af) {
        float4 f0 = *(const float4*)(af + base);
        float4 f1 = *(const float4*)(af + base + 4);
        v[0] = f0.x; v[1] = f0.y; v[2] = f0.z; v[3] = f0.w;
        v[4] = f1.x; v[5] = f1.y; v[6] = f1.z; v[7] = f1.w;
    } else {
        u16x8 hh = *(const u16x8*)(ah + base);
        u16x8 ll = *(const u16x8*)(ah + alo + base);
        for (int j = 0; j < 8; ++j) v[j] = bf2f(hh[j]) + bf2f(ll[j]);
    }
    if (bf) {
        float4 f0 = *(const float4*)(bf + base);
        float4 f1 = *(const float4*)(bf + base + 4);
        v[0] += f0.x; v[1] += f0.y; v[2] += f0.z; v[3] += f0.w;
        v[4] += f1.x; v[5] += f1.y; v[6] += f1.z; v[7] += f1.w;
    } else {
        u16x8 hh = *(const u16x8*)(bh + base);
        u16x8 ll = *(const u16x8*)(bh + blo + base);
        for (int j = 0; j < 8; ++j) v[j] += bf2f(hh[j]) + bf2f(ll[j]);
    }
    float s = 0.f, sq = 0.f;
    for (int j = 0; j < 8; ++j) { s += v[j]; sq += v[j] * v[j]; }
    for (int m = 1; m < 64; m <<= 1) { s += __shfl_xor(s, m); sq += __shfl_xor(sq, m); }
    const float mu = s * (1.f / 512.f);
    const float var = fmaxf(sq * (1.f / 512.f) - mu * mu, 0.f);
    const float rs = rsqrtf(var + 1e-5f);
    float4 ga = *(const float4*)(g + lane * 8);
    float4 gb = *(const float4*)(g + lane * 8 + 4);
    float4 ba = *(const float4*)(be + lane * 8);
    float4 bb = *(const float4*)(be + lane * 8 + 4);
    float gg[8] = {ga.x, ga.y, ga.z, ga.w, gb.x, gb.y, gb.z, gb.w};
    float bv[8] = {ba.x, ba.y, ba.z, ba.w, bb.x, bb.y, bb.z, bb.w};
    float o[8];
    for (int j = 0; j < 8; ++j) o[j] = (v[j] - mu) * rs * gg[j] + bv[j];
    if (of) {
        *(float4*)(of + base)     = make_float4(o[0], o[1], o[2], o[3]);
        *(float4*)(of + base + 4) = make_float4(o[4], o[5], o[6], o[7]);
    }
    if (oh) {
        u16x8 h8, l8;
        for (int j = 0; j < 8; ++j) { u16 hh, ll; split2(o[j], hh, ll); h8[j] = hh; l8[j] = ll; }
        *(u16x8*)(oh + base) = h8;
        *(u16x8*)(oh + olo + base) = l8;
    }
}

// Routing from hi/lo planes (argmax of logits). One wave per token.
__global__ __launch_bounds__(256) void route_p(
    const u16* __restrict__ xh, long xlo,
    const float* __restrict__ gw, const float* __restrict__ gb,
    int* __restrict__ idx)
{
    const int tid = threadIdx.x, lane = tid & 63, w = tid >> 6;
    const long row = (long)blockIdx.x * 4 + w;
    const long base = row * 512 + lane * 8;
    u16x8 hh = *(const u16x8*)(xh + base);
    u16x8 ll = *(const u16x8*)(xh + xlo + base);
    float xf[8];
    for (int j = 0; j < 8; ++j) xf[j] = bf2f(hh[j]) + bf2f(ll[j]);
    float d0 = 0.f, d1 = 0.f, d2 = 0.f, d3 = 0.f;
    {
        float4 w0 = *(const float4*)(gw + 0 * 512 + lane * 8);
        float4 w1 = *(const float4*)(gw + 0 * 512 + lane * 8 + 4);
        float wf[8] = {w0.x, w0.y, w0.z, w0.w, w1.x, w1.y, w1.z, w1.w};
        for (int j = 0; j < 8; ++j) d0 += xf[j] * wf[j];
    }
    {
        float4 w0 = *(const float4*)(gw + 1 * 512 + lane * 8);
        float4 w1 = *(const float4*)(gw + 1 * 512 + lane * 8 + 4);
        float wf[8] = {w0.x, w0.y, w0.z, w0.w, w1.x, w1.y, w1.z, w1.w};
        for (int j = 0; j < 8; ++j) d1 += xf[j] * wf[j];
    }
    {
        float4 w0 = *(const float4*)(gw + 2 * 512 + lane * 8);
        float4 w1 = *(const float4*)(gw + 2 * 512 + lane * 8 + 4);
        float wf[8] = {w0.x, w0.y, w0.z, w0.w, w1.x, w1.y, w1.z, w1.w};
        for (int j = 0; j < 8; ++j) d2 += xf[j] * wf[j];
    }
    {
        float4 w0 = *(const float4*)(gw + 3 * 512 + lane * 8);
        float4 w1 = *(const float4*)(gw + 3 * 512 + lane * 8 + 4);
        float wf[8] = {w0.x, w0.y, w0.z, w0.w, w1.x, w1.y, w1.z, w1.w};
        for (int j = 0; j < 8; ++j) d3 += xf[j] * wf[j];
    }
    for (int m = 1; m < 64; m <<= 1) {
        d0 += __shfl_xor(d0, m);
        d1 += __shfl_xor(d1, m);
        d2 += __shfl_xor(d2, m);
        d3 += __shfl_xor(d3, m);
    }
    if (lane == 0) {
        d0 += gb[0]; d1 += gb[1]; d2 += gb[2]; d3 += gb[3];
        float best = d0; int bi = 0;
        if (d1 > best) { best = d1; bi = 1; }
        if (d2 > best) { best = d2; bi = 2; }
        if (d3 > best) { best = d3; bi = 3; }
        idx[row] = bi;
    }
}

// Count idx + lay out expert regions. Single wave.
__global__ void plan_k(const int* __restrict__ idx, int* __restrict__ cursors,
                       int* __restrict__ tile_expert)
{
    int c0 = 0, c1 = 0, c2 = 0, c3 = 0;
    for (int i = threadIdx.x; i < 8192; i += 64) {
        const int e = idx[i];
        c0 += (e == 0); c1 += (e == 1); c2 += (e == 2); c3 += (e == 3);
    }
    for (int m = 1; m < 64; m <<= 1) {
        c0 += __shfl_xor(c0, m);
        c1 += __shfl_xor(c1, m);
        c2 += __shfl_xor(c2, m);
        c3 += __shfl_xor(c3, m);
    }
    if (threadIdx.x == 0) {
        int counts[4] = {c0, c1, c2, c3};
        int off = 0;
        for (int e = 0; e < 4; ++e) {
            cursors[e] = off;
            int nt = (counts[e] + 63) >> 6;
            int t0 = off >> 6;
            for (int i = 0; i < nt; ++i) tile_expert[t0 + i] = e;
            off += nt << 6;
        }
        for (int t = off >> 6; t < 132; ++t) tile_expert[t] = -1;
    }
}

// Scatter: per-block LDS histogram; one global atomic per block per expert.
__global__ __launch_bounds__(256) void scatter_k(
    const int* __restrict__ idx, int* __restrict__ cursors, int* __restrict__ perm)
{
    __shared__ int lcnt[4];
    __shared__ int lbase[4];
    const int t = blockIdx.x * 256 + threadIdx.x;
    if (threadIdx.x < 4) lcnt[threadIdx.x] = 0;
    __syncthreads();
    const int e = idx[t];
    const int lr = atomicAdd(&lcnt[e], 1);   // LDS atomic: local rank
    __syncthreads();
    if (threadIdx.x < 4)
        lbase[threadIdx.x] = atomicAdd(&cursors[threadIdx.x], lcnt[threadIdx.x]);
    __syncthreads();
    perm[lbase[e] + lr] = t;
}

// ===========================================================================
// R16: R15 plan (proven R5/R13 layout + z=4 attn) with gemm1_s (dbuf,
// 1-barrier) on the five 1-term GEMMs; gemm_s retained for 3-term out-projs.
// ===========================================================================
extern "C" void kernel_launch(void* const* d_in, const int* in_sizes, int n_in,
                              void* d_out, int out_size, void* d_ws, size_t ws_size,
                              hipStream_t stream)
{
    (void)in_sizes; (void)n_in; (void)out_size; (void)ws_size;
    const float* x        = (const float*)d_in[0];
    const float* mem      = (const float*)d_in[1];
    const float* sa_in_w  = (const float*)d_in[2];
    const float* sa_in_b  = (const float*)d_in[3];
    const float* sa_out_w = (const float*)d_in[4];
    const float* sa_out_b = (const float*)d_in[5];
    const float* ca_in_w  = (const float*)d_in[6];
    const float* ca_in_b  = (const float*)d_in[7];
    const float* ca_out_w = (const float*)d_in[8];
    const float* ca_out_b = (const float*)d_in[9];
    const float* gate_w   = (const float*)d_in[10];
    const float* gate_b   = (const float*)d_in[11];
    const float* w1       = (const float*)d_in[12];
    const float* b1       = (const float*)d_in[13];
    const float* w2       = (const float*)d_in[14];
    const float* b2       = (const float*)d_in[15];
    const float* ln1_g    = (const float*)d_in[16];
    const float* ln1_b    = (const float*)d_in[17];
    const float* ln2_g    = (const float*)d_in[18];
    const float* ln2_b    = (const float*)d_in[19];
    const float* ln3_g    = (const float*)d_in[20];
    const float* ln3_b    = (const float*)d_in[21];

    const float sc = 0.125f * 1.4426950408889634f;
    dim3 blk(256, 1, 1);
    char* ws = (char*)d_ws;

    // attn weight plane offsets (elements within WA)
    const long WAe_sa_in = 0, WAe_sa_out = 1572864, WAe_ca_in = 2097152, WAe_ca_out = 3670016;

    // -------- proven R5/R13 layout --------
    u16* WA   = (u16*)(ws);
    u16* w1h  = (u16*)(ws + 8388608L);
    u16* w2h  = (u16*)(ws + 16777216L);
    u16* QKVp = (u16*)(ws + 25165824L);   // 3 hi-only tensors, stride T; MoE H later
    u16* Op   = (u16*)(ws + 50331648L);   // hi+lo, lo at +L_8K
    u16* P1p  = (u16*)(ws + 67108864L);   // hi+lo out-proj result
    float* ymoe = (float*)(ws + 67108864L);
    u16* X1p  = (u16*)(ws + 83886080L);   // hi+lo residual
    int* idx    = (int*)(ws + 100663296L);
    int* perm   = (int*)(ws + 100663296L + 32768);
    int* cursors= (int*)(ws + 100663296L + 32768 + 33792 + 16);
    int* tile_e = (int*)(ws + 100663296L + 32768 + 33792 + 32);

    const long T    = 4194304;   // QKV tensor stride (hi-only), elements
    const long L_8K = 4194304;   // lo-plane offset for hi+lo tensors, elements

    hipMemsetAsync(perm, 0xFF, 8448 * 4, stream);

    split_k<<<dim3(384), blk, 0, stream>>>(sa_in_w,  WA + WAe_sa_in,  WA + WAe_sa_in + 786432, 786432);
    split_k<<<dim3(128), blk, 0, stream>>>(sa_out_w, WA + WAe_sa_out, WA + WAe_sa_out + 262144, 262144);
    split_k<<<dim3(384), blk, 0, stream>>>(ca_in_w,  WA + WAe_ca_in,  WA + WAe_ca_in + 786432, 786432);
    split_k<<<dim3(128), blk, 0, stream>>>(ca_out_w, WA + WAe_ca_out, WA + WAe_ca_out + 262144, 262144);
    splitT_k<<<dim3(32, 8, 4), blk, 0, stream>>>(w1, w1h, 512, 2048);
    splitT_k<<<dim3(8, 32, 4), blk, 0, stream>>>(w2, w2h, 2048, 512);

    // ---- self attention: full-row QKV (1-term, dbuf) + single z=4 attn ----
    gemm1_s<<<dim3(128, 24), blk, 0, stream>>>(
        x, nullptr, 512, nullptr,
        WA + WAe_sa_in, 512, 0, nullptr,
        sa_in_b, 0, nullptr, 0, nullptr,
        QKVp, 512, 9, T, 512, 0);
    attn_p<<<dim3(32, 8, 4), blk, 0, stream>>>(
        QKVp, QKVp + T, QKVp + 2 * T, 0, Op, L_8K, 0, sc);
    gemm_s<<<dim3(128, 8), blk, 0, stream>>>(
        nullptr, Op, Op + L_8K, 512, 1, nullptr,
        WA + WAe_sa_out, WA + WAe_sa_out + 262144, 512, 0, nullptr,
        sa_out_b, 0, nullptr, 0, nullptr,
        P1p, L_8K, 512, 9, 0, 512, 0);
    ln_p<<<dim3(2048), blk, 0, stream>>>(x, nullptr, 0, nullptr, P1p, L_8K,
                                         ln1_g, ln1_b, nullptr, X1p, L_8K);

    // ---- cross attention ----
    gemm1_s<<<dim3(128, 8), blk, 0, stream>>>(
        nullptr, X1p, 512, nullptr,
        WA + WAe_ca_in, 512, 0, nullptr,
        ca_in_b, 0, nullptr, 0, nullptr,
        QKVp, 512, 9, T, 512, 0);                       // Q -> tensor 0
    gemm1_s<<<dim3(128, 16), blk, 0, stream>>>(
        mem, nullptr, 512, nullptr,
        WA + WAe_ca_in + 262144, 512, 0, nullptr,
        ca_in_b + 512, 0, nullptr, 0, nullptr,
        QKVp + T, 512, 9, T, 512, 0);                   // K,V -> tensors 1,2
    attn_p<<<dim3(32, 8, 4), blk, 0, stream>>>(
        QKVp, QKVp + T, QKVp + 2 * T, 0, Op, L_8K, 0, sc);
    gemm_s<<<dim3(128, 8), blk, 0, stream>>>(
        nullptr, Op, Op + L_8K, 512, 1, nullptr,
        WA + WAe_ca_out, WA + WAe_ca_out + 262144, 512, 0, nullptr,
        ca_out_b, 0, nullptr, 0, nullptr,
        P1p, L_8K, 512, 9, 0, 512, 0);
    ln_p<<<dim3(2048), blk, 0, stream>>>(nullptr, X1p, L_8K, nullptr, P1p, L_8K,
                                         ln2_g, ln2_b, nullptr, X1p, L_8K);

    // ---- MoE (top-1, grouped; proven 2x66-tile chunking, H in QKVp) ----
    route_p<<<dim3(2048), blk, 0, stream>>>(X1p, L_8K, gate_w, gate_b, idx);
    plan_k<<<dim3(1), dim3(64), 0, stream>>>(idx, cursors, tile_e);
    scatter_k<<<dim3(32), blk, 0, stream>>>(idx, cursors, perm);
    for (int c = 0; c < 2; ++c) {
        const int t0 = c * 66;
        gemm1_s<<<dim3(66, 32), blk, 0, stream>>>(
            nullptr, X1p, 512, perm + t0 * 64,
            w1h, 512, 1048576, tile_e + t0,
            b1, 2048, nullptr, 0, nullptr,
            QKVp, 2048, 31, 0, 512, 1);
        gemm1_s<<<dim3(66, 8), blk, 0, stream>>>(
            nullptr, QKVp, 2048, nullptr,
            w2h, 2048, 1048576, tile_e + t0,
            b2, 512, ymoe, 512, perm + t0 * 64,
            nullptr, 0, 31, 0, 2048, 0);
    }
    ln_p<<<dim3(2048), blk, 0, stream>>>(nullptr, X1p, L_8K, ymoe, nullptr, 0,
                                         ln3_g, ln3_b, (float*)d_out, nullptr, 0);
}

// Round 13
// 620.175 us; speedup vs baseline: 1.1228x; 1.0558x over previous
//
#include <hip/hip_runtime.h>

typedef unsigned short u16;
typedef __attribute__((ext_vector_type(8))) short s16x8;
typedef __attribute__((ext_vector_type(8))) unsigned short u16x8;
typedef __attribute__((ext_vector_type(4))) unsigned short u16x4;
typedef __attribute__((ext_vector_type(4))) float f32x4;

#define DEV static __device__ __forceinline__
#define MFMA __builtin_amdgcn_mfma_f32_16x16x32_bf16

DEV float bf2f(u16 u) { return __uint_as_float(((unsigned)u) << 16); }
DEV u16 f2bf(float f) {
    unsigned u = __float_as_uint(f);
    return (u16)((u + 0x7FFFu + ((u >> 16) & 1u)) >> 16);
}
DEV void split2(float v, u16& hi, u16& lo) {
    hi = f2bf(v);
    lo = f2bf(v - bf2f(hi));
}

// ===========================================================================
// bf16 hi/lo plane pipeline kernels (verified R5/R13/R16)
// ===========================================================================

// Split fp32 -> bf16 hi/lo planes, elementwise. n multiple of 2048.
__global__ __launch_bounds__(256) void split_k(
    const float* __restrict__ src, u16* __restrict__ dh, u16* __restrict__ dl, long n)
{
    const long i = ((long)blockIdx.x * 256 + threadIdx.x) * 8;
    if (i >= n) return;
    float4 f0 = *(const float4*)(src + i);
    float4 f1 = *(const float4*)(src + i + 4);
    float v[8] = {f0.x, f0.y, f0.z, f0.w, f1.x, f1.y, f1.z, f1.w};
    u16x8 h8, l8;
    for (int j = 0; j < 8; ++j) { u16 hh, ll; split2(v[j], hh, ll); h8[j] = hh; l8[j] = ll; }
    *(u16x8*)(dh + i) = h8;
    *(u16x8*)(dl + i) = l8;
}

// Transpose+split (hi only): src [E][K][N] fp32 -> dst [E][N][K] bf16.
__global__ __launch_bounds__(256) void splitT_k(
    const float* __restrict__ src, u16* __restrict__ dst, int K, int N)
{
    __shared__ u16 tile[64 * 72];
    const int e = blockIdx.z;
    const int n0 = blockIdx.x * 64, k0 = blockIdx.y * 64;
    const long estride = (long)K * N;
    const int tid = threadIdx.x;
    const int tr = tid >> 2, tc = (tid & 3) * 16;
    {
        const float* sp = src + e * estride + (long)(k0 + tr) * N + n0 + tc;
        for (int j = 0; j < 16; j += 4) {
            float4 f = *(const float4*)(sp + j);
            tile[tr * 72 + tc + j + 0] = f2bf(f.x);
            tile[tr * 72 + tc + j + 1] = f2bf(f.y);
            tile[tr * 72 + tc + j + 2] = f2bf(f.z);
            tile[tr * 72 + tc + j + 3] = f2bf(f.w);
        }
    }
    __syncthreads();
    {
        const int tn = tid >> 2, tk = (tid & 3) * 16;
        u16* dp = dst + e * estride + (long)(n0 + tn) * K + k0 + tk;
        u16x8 o0, o1;
        for (int j = 0; j < 8; ++j) {
            o0[j] = tile[(tk + j) * 72 + tn];
            o1[j] = tile[(tk + 8 + j) * 72 + tn];
        }
        *(u16x8*)(dp) = o0;
        *(u16x8*)(dp + 8) = o1;
    }
}

// ---------------------------------------------------------------------------
// gemm128_s (R17): dense 1-term bf16 GEMM, 128x128 C tile, 4 waves each
// owning a 64x64 quadrant via 4x4 16x16 fragments -> 16 MFMA + 8 ds_read
// per wave per barrier (4x the MFMA:barrier ratio of the 64^2 tile; ladder
// m92->m93 = +51%). Double-buffered LDS, one barrier per k-step, prefetch
// issued before compute (R16 pattern). Stride-36 LDS (proven conflict-free).
// LDS 36.9 KB; acc[4][4] ~64 VGPR. Dense only: no perm, no experts.
// A: fp32 (converted at staging) or bf16 hi plane. C: hi plane w/ ts route.
// Accumulation order per output element identical to gemm1_s (bit-identical).
// ---------------------------------------------------------------------------
__global__ __launch_bounds__(256) void gemm128_s(
    const float* __restrict__ Af, const u16* __restrict__ Ahp, int lda,
    const u16* __restrict__ Bh, int ldb,
    const float* __restrict__ bias,
    u16* __restrict__ Ch, int ldcp, int ts, long tstride, int K)
{
    __shared__ u16 As[2][128 * 36], Bs[2][128 * 36];
    const int mt = blockIdx.x, nt = blockIdx.y;
    const int tid = threadIdx.x, lane = tid & 63, w = tid >> 6;
    const int wr = (w >> 1) * 64, wc = (w & 1) * 64;
    const int quad = lane >> 4, l15 = lane & 15;

    const int r1 = tid >> 2, c8 = (tid & 3) * 8;   // bf16 staging: rows r1, r1+64
    const int r2 = tid >> 3, c4 = (tid & 7) * 4;   // fp32 staging: rows r2+32h
    const long arow = (long)mt * 128;
    const long brow = (long)nt * 128;

    f32x4 acc[4][4] = {};
    const int NT = K >> 5;

    u16x8 ra0, ra1, rb0, rb1;
    float4 f0, f1, f2, f3;

    // load tile 0
    if (Af) {
        f0 = *(const float4*)(Af + (arow + r2) * (long)lda + c4);
        f1 = *(const float4*)(Af + (arow + r2 + 32) * (long)lda + c4);
        f2 = *(const float4*)(Af + (arow + r2 + 64) * (long)lda + c4);
        f3 = *(const float4*)(Af + (arow + r2 + 96) * (long)lda + c4);
    } else {
        ra0 = *(const u16x8*)(Ahp + (arow + r1) * (long)lda + c8);
        ra1 = *(const u16x8*)(Ahp + (arow + r1 + 64) * (long)lda + c8);
    }
    rb0 = *(const u16x8*)(Bh + (brow + r1) * (long)ldb + c8);
    rb1 = *(const u16x8*)(Bh + (brow + r1 + 64) * (long)ldb + c8);
    // stage tile 0 into buf 0
    if (Af) {
        u16x4 h4;
        float t0[4] = {f0.x, f0.y, f0.z, f0.w};
        for (int i = 0; i < 4; ++i) h4[i] = f2bf(t0[i]);
        *(u16x4*)&As[0][r2 * 36 + c4] = h4;
        float t1[4] = {f1.x, f1.y, f1.z, f1.w};
        for (int i = 0; i < 4; ++i) h4[i] = f2bf(t1[i]);
        *(u16x4*)&As[0][(r2 + 32) * 36 + c4] = h4;
        float t2[4] = {f2.x, f2.y, f2.z, f2.w};
        for (int i = 0; i < 4; ++i) h4[i] = f2bf(t2[i]);
        *(u16x4*)&As[0][(r2 + 64) * 36 + c4] = h4;
        float t3[4] = {f3.x, f3.y, f3.z, f3.w};
        for (int i = 0; i < 4; ++i) h4[i] = f2bf(t3[i]);
        *(u16x4*)&As[0][(r2 + 96) * 36 + c4] = h4;
    } else {
        *(u16x8*)&As[0][r1 * 36 + c8] = ra0;
        *(u16x8*)&As[0][(r1 + 64) * 36 + c8] = ra1;
    }
    *(u16x8*)&Bs[0][r1 * 36 + c8] = rb0;
    *(u16x8*)&Bs[0][(r1 + 64) * 36 + c8] = rb1;

    for (int t = 0; t < NT; ++t) {
        const int cur = t & 1;
        __syncthreads();   // buf[cur] staged; buf[cur^1] readers done
        if (t + 1 < NT) {  // issue next tile's loads (in flight across compute)
            const int k0 = (t + 1) * 32;
            if (Af) {
                f0 = *(const float4*)(Af + (arow + r2) * (long)lda + k0 + c4);
                f1 = *(const float4*)(Af + (arow + r2 + 32) * (long)lda + k0 + c4);
                f2 = *(const float4*)(Af + (arow + r2 + 64) * (long)lda + k0 + c4);
                f3 = *(const float4*)(Af + (arow + r2 + 96) * (long)lda + k0 + c4);
            } else {
                ra0 = *(const u16x8*)(Ahp + (arow + r1) * (long)lda + k0 + c8);
                ra1 = *(const u16x8*)(Ahp + (arow + r1 + 64) * (long)lda + k0 + c8);
            }
            rb0 = *(const u16x8*)(Bh + (brow + r1) * (long)ldb + k0 + c8);
            rb1 = *(const u16x8*)(Bh + (brow + r1 + 64) * (long)ldb + k0 + c8);
        }
        {
            s16x8 a[4], b[4];
            #pragma unroll
            for (int i = 0; i < 4; ++i) {
                a[i] = *(const s16x8*)&As[cur][(wr + i * 16 + l15) * 36 + quad * 8];
                b[i] = *(const s16x8*)&Bs[cur][(wc + i * 16 + l15) * 36 + quad * 8];
            }
            __builtin_amdgcn_s_setprio(1);
            #pragma unroll
            for (int i = 0; i < 4; ++i)
                #pragma unroll
                for (int j = 0; j < 4; ++j)
                    acc[i][j] = MFMA(a[i], b[j], acc[i][j], 0, 0, 0);
            __builtin_amdgcn_s_setprio(0);
        }
        if (t + 1 < NT) {   // stage next tile into the other buffer
            const int nx = cur ^ 1;
            if (Af) {
                u16x4 h4;
                float t0[4] = {f0.x, f0.y, f0.z, f0.w};
                for (int i = 0; i < 4; ++i) h4[i] = f2bf(t0[i]);
                *(u16x4*)&As[nx][r2 * 36 + c4] = h4;
                float t1[4] = {f1.x, f1.y, f1.z, f1.w};
                for (int i = 0; i < 4; ++i) h4[i] = f2bf(t1[i]);
                *(u16x4*)&As[nx][(r2 + 32) * 36 + c4] = h4;
                float t2[4] = {f2.x, f2.y, f2.z, f2.w};
                for (int i = 0; i < 4; ++i) h4[i] = f2bf(t2[i]);
                *(u16x4*)&As[nx][(r2 + 64) * 36 + c4] = h4;
                float t3[4] = {f3.x, f3.y, f3.z, f3.w};
                for (int i = 0; i < 4; ++i) h4[i] = f2bf(t3[i]);
                *(u16x4*)&As[nx][(r2 + 96) * 36 + c4] = h4;
            } else {
                *(u16x8*)&As[nx][r1 * 36 + c8] = ra0;
                *(u16x8*)&As[nx][(r1 + 64) * 36 + c8] = ra1;
            }
            *(u16x8*)&Bs[nx][r1 * 36 + c8] = rb0;
            *(u16x8*)&Bs[nx][(r1 + 64) * 36 + c8] = rb1;
        }
    }

    for (int i = 0; i < 4; ++i) {
        for (int r = 0; r < 4; ++r) {
            const int rloc = wr + i * 16 + quad * 4 + r;  // C/D: row=(lane>>4)*4+reg
            const long lrow = (long)mt * 128 + rloc;
            for (int j = 0; j < 4; ++j) {
                const int colg = nt * 128 + wc + j * 16 + l15;  // C/D: col=lane&15
                const float v = acc[i][j][r] + bias[colg];
                const int tq = colg >> ts;
                const int cc = colg - (tq << ts);
                Ch[(long)tq * tstride + lrow * (long)ldcp + cc] = f2bf(v);
            }
        }
    }
}

// ---------------------------------------------------------------------------
// gemm1_s: 1-term bf16 GEMM, 64^2 tile, dbuf, one barrier per k-step
// (verified R16). Used for MoE (perm/expert) GEMMs.
// ---------------------------------------------------------------------------
__global__ __launch_bounds__(256) void gemm1_s(
    const float* __restrict__ Af, const u16* __restrict__ Ahp,
    int lda, const int* __restrict__ perm_in,
    const u16* __restrict__ Bh, int ldb, long b_estride,
    const int* __restrict__ tile_expert,
    const float* __restrict__ bias, int bias_estride,
    float* __restrict__ Cf, int ldcf, const int* __restrict__ perm_out,
    u16* __restrict__ Ch, int ldcp, int ts, long tstride,
    int K, int act)
{
    __shared__ u16 As[2][64 * 36], Bs[2][64 * 36];
    const int mt = blockIdx.x, nt = blockIdx.y;
    int e = 0;
    if (tile_expert) { e = tile_expert[mt]; if (e < 0) return; }
    const int tid = threadIdx.x, lane = tid & 63, w = tid >> 6;
    const int wr = (w >> 1) * 32, wc = (w & 1) * 32;
    const int quad = lane >> 4, l15 = lane & 15;

    const u16* Bhb = Bh + (long)e * b_estride;

    const int r2 = tid >> 3, c4 = (tid & 7) * 4;   // fp32-A staging
    const int r1 = tid >> 2, c8 = (tid & 3) * 8;   // plane staging
    long arow0 = 0, arow1 = 0, arowb = 0;
    bool v0 = true, v1 = true, vb = true;
    if (perm_in) {
        if (Af) {
            int p0 = perm_in[mt * 64 + r2];      v0 = p0 >= 0; arow0 = p0 < 0 ? 0 : p0;
            int p1 = perm_in[mt * 64 + r2 + 32]; v1 = p1 >= 0; arow1 = p1 < 0 ? 0 : p1;
        } else {
            int pb = perm_in[mt * 64 + r1];      vb = pb >= 0; arowb = pb < 0 ? 0 : pb;
        }
    } else {
        arow0 = (long)mt * 64 + r2; arow1 = arow0 + 32; arowb = (long)mt * 64 + r1;
    }

    f32x4 acc[2][2] = {};
    const int NT = K >> 5;

    u16x8 ra, rb;
    float4 fa0, fa1;

    if (Af) {
        fa0 = v0 ? *(const float4*)(Af + arow0 * (long)lda + c4) : make_float4(0.f, 0.f, 0.f, 0.f);
        fa1 = v1 ? *(const float4*)(Af + arow1 * (long)lda + c4) : make_float4(0.f, 0.f, 0.f, 0.f);
    } else {
        ra = vb ? *(const u16x8*)(Ahp + arowb * (long)lda + c8) : (u16x8)(u16)0;
    }
    rb = *(const u16x8*)(Bhb + ((long)nt * 64 + r1) * ldb + c8);
    if (Af) {
        u16x4 h4;
        float t0a[4] = {fa0.x, fa0.y, fa0.z, fa0.w};
        for (int i = 0; i < 4; ++i) h4[i] = f2bf(t0a[i]);
        *(u16x4*)&As[0][r2 * 36 + c4] = h4;
        float t0b[4] = {fa1.x, fa1.y, fa1.z, fa1.w};
        for (int i = 0; i < 4; ++i) h4[i] = f2bf(t0b[i]);
        *(u16x4*)&As[0][(32 + r2) * 36 + c4] = h4;
    } else {
        *(u16x8*)&As[0][r1 * 36 + c8] = ra;
    }
    *(u16x8*)&Bs[0][r1 * 36 + c8] = rb;

    for (int t = 0; t < NT; ++t) {
        const int cur = t & 1;
        __syncthreads();
        if (t + 1 < NT) {
            const int k0 = (t + 1) * 32;
            if (Af) {
                fa0 = v0 ? *(const float4*)(Af + arow0 * (long)lda + k0 + c4) : make_float4(0.f, 0.f, 0.f, 0.f);
                fa1 = v1 ? *(const float4*)(Af + arow1 * (long)lda + k0 + c4) : make_float4(0.f, 0.f, 0.f, 0.f);
            } else {
                ra = vb ? *(const u16x8*)(Ahp + arowb * (long)lda + k0 + c8) : (u16x8)(u16)0;
            }
            rb = *(const u16x8*)(Bhb + ((long)nt * 64 + r1) * ldb + k0 + c8);
        }
        {
            s16x8 ah0 = *(const s16x8*)&As[cur][(wr + l15) * 36 + quad * 8];
            s16x8 ah1 = *(const s16x8*)&As[cur][(wr + 16 + l15) * 36 + quad * 8];
            s16x8 bh0 = *(const s16x8*)&Bs[cur][(wc + l15) * 36 + quad * 8];
            s16x8 bh1 = *(const s16x8*)&Bs[cur][(wc + 16 + l15) * 36 + quad * 8];
            __builtin_amdgcn_s_setprio(1);
            acc[0][0] = MFMA(ah0, bh0, acc[0][0], 0, 0, 0);
            acc[0][1] = MFMA(ah0, bh1, acc[0][1], 0, 0, 0);
            acc[1][0] = MFMA(ah1, bh0, acc[1][0], 0, 0, 0);
            acc[1][1] = MFMA(ah1, bh1, acc[1][1], 0, 0, 0);
            __builtin_amdgcn_s_setprio(0);
        }
        if (t + 1 < NT) {
            const int nx = cur ^ 1;
            if (Af) {
                u16x4 h4;
                float tna[4] = {fa0.x, fa0.y, fa0.z, fa0.w};
                for (int i = 0; i < 4; ++i) h4[i] = f2bf(tna[i]);
                *(u16x4*)&As[nx][r2 * 36 + c4] = h4;
                float tnb[4] = {fa1.x, fa1.y, fa1.z, fa1.w};
                for (int i = 0; i < 4; ++i) h4[i] = f2bf(tnb[i]);
                *(u16x4*)&As[nx][(32 + r2) * 36 + c4] = h4;
            } else {
                *(u16x8*)&As[nx][r1 * 36 + c8] = ra;
            }
            *(u16x8*)&Bs[nx][r1 * 36 + c8] = rb;
        }
    }

    const float* bp = bias + (long)e * bias_estride;
    for (int mi = 0; mi < 2; ++mi) {
        for (int r = 0; r < 4; ++r) {
            const int rloc = wr + mi * 16 + quad * 4 + r;
            const long lrow = (long)mt * 64 + rloc;
            for (int ni = 0; ni < 2; ++ni) {
                const int colg = nt * 64 + wc + ni * 16 + l15;
                float v = acc[mi][ni][r] + bp[colg];
                if (act == 1) v = 0.5f * v * (1.f + erff(v * 0.7071067811865475f));
                if (Cf) {
                    long orow = lrow;
                    if (perm_out) { int po = perm_out[mt * 64 + rloc]; if (po < 0) continue; orow = po; }
                    Cf[orow * (long)ldcf + colg] = v;
                }
                if (Ch) {
                    const int tq = colg >> ts;
                    const int cc = colg - (tq << ts);
                    Ch[(long)tq * tstride + lrow * (long)ldcp + cc] = f2bf(v);
                }
            }
        }
    }
}

// ---------------------------------------------------------------------------
// GEMM (plane pipeline, 3-term): retained for the two out-projections.
// ---------------------------------------------------------------------------
__global__ __launch_bounds__(256) void gemm_s(
    const float* __restrict__ Af, const u16* __restrict__ Ahp, const u16* __restrict__ Alp,
    int lda, int a_lo, const int* __restrict__ perm_in,
    const u16* __restrict__ Bh, const u16* __restrict__ Bl, int ldb, long b_estride,
    const int* __restrict__ tile_expert,
    const float* __restrict__ bias, int bias_estride,
    float* __restrict__ Cf, int ldcf, const int* __restrict__ perm_out,
    u16* __restrict__ Ch, long clo_off, int ldcp, int ts, long tstride,
    int K, int act)
{
    __shared__ u16 As[64 * 36], Als[64 * 36];
    __shared__ u16 Bs[64 * 36], Bls[64 * 36];
    const int mt = blockIdx.x, nt = blockIdx.y;
    int e = 0;
    if (tile_expert) { e = tile_expert[mt]; if (e < 0) return; }
    const int tid = threadIdx.x, lane = tid & 63, w = tid >> 6;
    const int wr = (w >> 1) * 32, wc = (w & 1) * 32;
    const int quad = lane >> 4, l15 = lane & 15;
    const int b_lo = (Bl != nullptr);

    const u16* Bhb = Bh + (long)e * b_estride;
    const u16* Blb = b_lo ? (Bl + (long)e * b_estride) : nullptr;

    const int r2 = tid >> 3, c4 = (tid & 7) * 4;
    const int r1 = tid >> 2, c8 = (tid & 3) * 8;
    long arow0 = 0, arow1 = 0, arowb = 0;
    bool v0 = true, v1 = true, vb = true;
    if (perm_in) {
        if (Af) {
            int p0 = perm_in[mt * 64 + r2];      v0 = p0 >= 0; arow0 = p0 < 0 ? 0 : p0;
            int p1 = perm_in[mt * 64 + r2 + 32]; v1 = p1 >= 0; arow1 = p1 < 0 ? 0 : p1;
        } else {
            int pb = perm_in[mt * 64 + r1];      vb = pb >= 0; arowb = pb < 0 ? 0 : pb;
        }
    } else {
        arow0 = (long)mt * 64 + r2; arow1 = arow0 + 32; arowb = (long)mt * 64 + r1;
    }

    f32x4 acc[2][2] = {};

    for (int k0 = 0; k0 < K; k0 += 32) {
        __syncthreads();
        if (Af) {
            for (int half = 0; half < 2; ++half) {
                const int row = half * 32 + r2;
                const long ar = half ? arow1 : arow0;
                const bool va = half ? v1 : v0;
                float4 v = va ? *(const float4*)(Af + ar * (long)lda + k0 + c4)
                              : make_float4(0.f, 0.f, 0.f, 0.f);
                float vv[4] = {v.x, v.y, v.z, v.w};
                u16x4 h4, l4;
                for (int i = 0; i < 4; ++i) { u16 hh, ll; split2(vv[i], hh, ll); h4[i] = hh; l4[i] = ll; }
                *(u16x4*)&As[row * 36 + c4] = h4;
                if (a_lo) *(u16x4*)&Als[row * 36 + c4] = l4;
            }
        } else {
            const long ao = arowb * (long)lda + k0 + c8;
            u16x8 h8 = vb ? *(const u16x8*)(Ahp + ao) : (u16x8)(u16)0;
            *(u16x8*)&As[r1 * 36 + c8] = h8;
            if (a_lo) {
                u16x8 l8 = vb ? *(const u16x8*)(Alp + ao) : (u16x8)(u16)0;
                *(u16x8*)&Als[r1 * 36 + c8] = l8;
            }
        }
        {
            const long bo = ((long)nt * 64 + r1) * ldb + k0 + c8;
            *(u16x8*)&Bs[r1 * 36 + c8] = *(const u16x8*)(Bhb + bo);
            if (b_lo) *(u16x8*)&Bls[r1 * 36 + c8] = *(const u16x8*)(Blb + bo);
        }
        __syncthreads();
        s16x8 ah0 = *(const s16x8*)&As[(wr + l15) * 36 + quad * 8];
        s16x8 ah1 = *(const s16x8*)&As[(wr + 16 + l15) * 36 + quad * 8];
        s16x8 bh0 = *(const s16x8*)&Bs[(wc + l15) * 36 + quad * 8];
        s16x8 bh1 = *(const s16x8*)&Bs[(wc + 16 + l15) * 36 + quad * 8];
        acc[0][0] = MFMA(ah0, bh0, acc[0][0], 0, 0, 0);
        acc[0][1] = MFMA(ah0, bh1, acc[0][1], 0, 0, 0);
        acc[1][0] = MFMA(ah1, bh0, acc[1][0], 0, 0, 0);
        acc[1][1] = MFMA(ah1, bh1, acc[1][1], 0, 0, 0);
        if (a_lo) {
            s16x8 al0 = *(const s16x8*)&Als[(wr + l15) * 36 + quad * 8];
            s16x8 al1 = *(const s16x8*)&Als[(wr + 16 + l15) * 36 + quad * 8];
            acc[0][0] = MFMA(al0, bh0, acc[0][0], 0, 0, 0);
            acc[0][1] = MFMA(al0, bh1, acc[0][1], 0, 0, 0);
            acc[1][0] = MFMA(al1, bh0, acc[1][0], 0, 0, 0);
            acc[1][1] = MFMA(al1, bh1, acc[1][1], 0, 0, 0);
        }
        if (b_lo) {
            s16x8 bl0 = *(const s16x8*)&Bls[(wc + l15) * 36 + quad * 8];
            s16x8 bl1 = *(const s16x8*)&Bls[(wc + 16 + l15) * 36 + quad * 8];
            acc[0][0] = MFMA(ah0, bl0, acc[0][0], 0, 0, 0);
            acc[0][1] = MFMA(ah0, bl1, acc[0][1], 0, 0, 0);
            acc[1][0] = MFMA(ah1, bl0, acc[1][0], 0, 0, 0);
            acc[1][1] = MFMA(ah1, bl1, acc[1][1], 0, 0, 0);
        }
    }

    const float* bp = bias + (long)e * bias_estride;
    for (int mi = 0; mi < 2; ++mi) {
        for (int r = 0; r < 4; ++r) {
            const int rloc = wr + mi * 16 + quad * 4 + r;
            const long lrow = (long)mt * 64 + rloc;
            for (int ni = 0; ni < 2; ++ni) {
                const int colg = nt * 64 + wc + ni * 16 + l15;
                float v = acc[mi][ni][r] + bp[colg];
                if (act == 1) v = 0.5f * v * (1.f + erff(v * 0.7071067811865475f));
                if (Cf) {
                    long orow = lrow;
                    if (perm_out) { int po = perm_out[mt * 64 + rloc]; if (po < 0) continue; orow = po; }
                    Cf[orow * (long)ldcf + colg] = v;
                }
                if (Ch) {
                    const int t = colg >> ts;
                    const int cc = colg - (t << ts);
                    const long po = (long)t * tstride + lrow * (long)ldcp + cc;
                    u16 hh, ll; split2(v, hh, ll);
                    Ch[po] = hh;
                    if (clo_off) Ch[po + clo_off] = ll;
                }
            }
        }
    }
}

// ---------------------------------------------------------------------------
// Flash attention, single-plane bf16 (R12/R13 verified; z=4 launch).
// ---------------------------------------------------------------------------
__global__ __launch_bounds__(256) void attn_p(
    const u16* __restrict__ Qh, const u16* __restrict__ Kh, const u16* __restrict__ Vh,
    long plo, u16* __restrict__ Oh, long olo, int orow_base, float sc)
{
    (void)plo;
    __shared__ u16 Khs[2][64 * 80];
    __shared__ u16 Vhs[2][2][64 * 36];
    const int Z = gridDim.z;
    const int lin = blockIdx.x + 32 * (blockIdx.y + 8 * blockIdx.z);
    const int g = lin & 7, li = lin >> 3;
    const int p = g * Z + (li >> 5);
    const int qt = li & 31;
    const int h = p & 7, z = p >> 3;

    const int tid = threadIdx.x, lane = tid & 63, w = tid >> 6;
    const int quad = lane >> 4, l15 = lane & 15;

    const long qoff = ((long)z * 2048 + qt * 64 + w * 16 + l15) * 512 + h * 64 + quad * 8;
    s16x8 q0, q1;
    {
        s16x8 q0r = *(const s16x8*)(Qh + qoff);
        s16x8 q1r = *(const s16x8*)(Qh + qoff + 32);
        #pragma unroll
        for (int j = 0; j < 8; ++j) {
            q0[j] = (short)f2bf(bf2f((u16)q0r[j]) * sc);
            q1[j] = (short)f2bf(bf2f((u16)q1r[j]) * sc);
        }
    }

    const int kr = tid >> 3, kc = (tid & 7) * 8;
    const int vkey = tid & 31, vhd0 = (tid >> 5) * 8;
    const int vslot = ((vkey >> 2) & 3) * 8 + (vkey & 3) + ((vkey >> 4) << 2);
    const long kbase = ((long)z * 2048 + kr) * 512 + h * 64 + kc;
    const long vbase = ((long)z * 2048 + vkey) * 512 + h * 64 + vhd0;

    {
        u16x8 ka = *(const u16x8*)(Kh + kbase);
        u16x8 kb = *(const u16x8*)(Kh + kbase + 32L * 512);
        u16x8 va = *(const u16x8*)(Vh + vbase);
        u16x8 vb = *(const u16x8*)(Vh + vbase + 32L * 512);
        *(u16x8*)&Khs[0][kr * 80 + kc] = ka;
        *(u16x8*)&Khs[0][(kr + 32) * 80 + kc] = kb;
        #pragma unroll
        for (int i = 0; i < 8; ++i) {
            Vhs[0][0][(vhd0 + i) * 36 + vslot] = va[i];
            Vhs[0][1][(vhd0 + i) * 36 + vslot] = vb[i];
        }
    }

    float l_run = 0.f;
    f32x4 oacc[4] = {};

    for (int t = 0; t < 32; ++t) {
        const int cur = t & 1;
        __syncthreads();
        u16x8 kna, knb, vna, vnb;
        if (t < 31) {
            const long o = (long)(t + 1) * 32768;
            kna = *(const u16x8*)(Kh + kbase + o);
            knb = *(const u16x8*)(Kh + kbase + 32L * 512 + o);
            vna = *(const u16x8*)(Vh + vbase + o);
            vnb = *(const u16x8*)(Vh + vbase + 32L * 512 + o);
        }
        const u16* Kc = Khs[cur];
        f32x4 s0a = {0.f, 0.f, 0.f, 0.f}, s1a = {0.f, 0.f, 0.f, 0.f};
        f32x4 s0b = {0.f, 0.f, 0.f, 0.f}, s1b = {0.f, 0.f, 0.f, 0.f};
        {
            s16x8 a00 = *(const s16x8*)&Kc[l15 * 80 + quad * 8];
            s16x8 a01 = *(const s16x8*)&Kc[l15 * 80 + 32 + quad * 8];
            s16x8 a10 = *(const s16x8*)&Kc[(16 + l15) * 80 + quad * 8];
            s16x8 a11 = *(const s16x8*)&Kc[(16 + l15) * 80 + 32 + quad * 8];
            s16x8 b00 = *(const s16x8*)&Kc[(32 + l15) * 80 + quad * 8];
            s16x8 b01 = *(const s16x8*)&Kc[(32 + l15) * 80 + 32 + quad * 8];
            s16x8 b10 = *(const s16x8*)&Kc[(48 + l15) * 80 + quad * 8];
            s16x8 b11 = *(const s16x8*)&Kc[(48 + l15) * 80 + 32 + quad * 8];
            __builtin_amdgcn_s_setprio(1);
            s0a = MFMA(a00, q0, s0a, 0, 0, 0);
            s1a = MFMA(a10, q0, s1a, 0, 0, 0);
            s0b = MFMA(b00, q0, s0b, 0, 0, 0);
            s1b = MFMA(b10, q0, s1b, 0, 0, 0);
            s0a = MFMA(a01, q1, s0a, 0, 0, 0);
            s1a = MFMA(a11, q1, s1a, 0, 0, 0);
            s0b = MFMA(b01, q1, s0b, 0, 0, 0);
            s1b = MFMA(b11, q1, s1b, 0, 0, 0);
            __builtin_amdgcn_s_setprio(0);
        }
        float pa[8], pb[8];
        pa[0] = exp2f(s0a[0]); pa[1] = exp2f(s0a[1]);
        pa[2] = exp2f(s0a[2]); pa[3] = exp2f(s0a[3]);
        pa[4] = exp2f(s1a[0]); pa[5] = exp2f(s1a[1]);
        pa[6] = exp2f(s1a[2]); pa[7] = exp2f(s1a[3]);
        pb[0] = exp2f(s0b[0]); pb[1] = exp2f(s0b[1]);
        pb[2] = exp2f(s0b[2]); pb[3] = exp2f(s0b[3]);
        pb[4] = exp2f(s1b[0]); pb[5] = exp2f(s1b[1]);
        pb[6] = exp2f(s1b[2]); pb[7] = exp2f(s1b[3]);
        l_run += (((pa[0] + pa[1]) + (pa[2] + pa[3])) +
                  ((pa[4] + pa[5]) + (pa[6] + pa[7]))) +
                 (((pb[0] + pb[1]) + (pb[2] + pb[3])) +
                  ((pb[4] + pb[5]) + (pb[6] + pb[7])));
        s16x8 pha, phb;
        #pragma unroll
        for (int j = 0; j < 8; ++j) {
            pha[j] = (short)(__float_as_uint(pa[j]) >> 16);
            phb[j] = (short)(__float_as_uint(pb[j]) >> 16);
        }
        __builtin_amdgcn_s_setprio(1);
        #pragma unroll
        for (int tt = 0; tt < 4; ++tt) {
            s16x8 vha = *(const s16x8*)&Vhs[cur][0][(tt * 16 + l15) * 36 + quad * 8];
            s16x8 vhb = *(const s16x8*)&Vhs[cur][1][(tt * 16 + l15) * 36 + quad * 8];
            oacc[tt] = MFMA(pha, vha, oacc[tt], 0, 0, 0);
            oacc[tt] = MFMA(phb, vhb, oacc[tt], 0, 0, 0);
        }
        __builtin_amdgcn_s_setprio(0);
        if (t < 31) {
            u16* Kn = (u16*)Khs[cur ^ 1];
            *(u16x8*)&Kn[kr * 80 + kc] = kna;
            *(u16x8*)&Kn[(kr + 32) * 80 + kc] = knb;
            #pragma unroll
            for (int i = 0; i < 8; ++i) {
                Vhs[cur ^ 1][0][(vhd0 + i) * 36 + vslot] = vna[i];
                Vhs[cur ^ 1][1][(vhd0 + i) * 36 + vslot] = vnb[i];
            }
        }
    }

    l_run += __shfl_xor(l_run, 16);
    l_run += __shfl_xor(l_run, 32);
    float linv[4];
    #pragma unroll
    for (int r = 0; r < 4; ++r)
        linv[r] = 1.f / fmaxf(__shfl(l_run, quad * 4 + r), 1e-35f);
    const long obase = ((long)orow_base + z * 2048 + qt * 64 + w * 16 + quad * 4) * 512 + h * 64;
    for (int tt = 0; tt < 4; ++tt)
        for (int r = 0; r < 4; ++r) {
            u16 hh, ll; split2(oacc[tt][r] * linv[r], hh, ll);
            const long oo = obase + (long)r * 512 + tt * 16 + l15;
            Oh[oo] = hh;
            Oh[olo + oo] = ll;
        }
}

// ---------------------------------------------------------------------------
// Residual + LayerNorm (D=512).
// ---------------------------------------------------------------------------
__global__ __launch_bounds__(256) void ln_p(
    const float* __restrict__ af, const u16* __restrict__ ah, long alo,
    const float* __restrict__ bf, const u16* __restrict__ bh, long blo,
    const float* __restrict__ g, const float* __restrict__ be,
    float* __restrict__ of, u16* __restrict__ oh, long olo)
{
    const int tid = threadIdx.x, lane = tid & 63, w = tid >> 6;
    const long base = ((long)blockIdx.x * 4 + w) * 512 + lane * 8;
    float v[8];
    if (af) {
        float4 f0 = *(const float4*)(af + base);
        float4 f1 = *(const float4*)(af + base + 4);
        v[0] = f0.x; v[1] = f0.y; v[2] = f0.z; v[3] = f0.w;
        v[4] = f1.x; v[5] = f1.y; v[6] = f1.z; v[7] = f1.w;
    } else {
        u16x8 hh = *(const u16x8*)(ah + base);
        u16x8 ll = *(const u16x8*)(ah + alo + base);
        for (int j = 0; j < 8; ++j) v[j] = bf2f(hh[j]) + bf2f(ll[j]);
    }
    if (bf) {
        float4 f0 = *(const float4*)(bf + base);
        float4 f1 = *(const float4*)(bf + base + 4);
        v[0] += f0.x; v[1] += f0.y; v[2] += f0.z; v[3] += f0.w;
        v[4] += f1.x; v[5] += f1.y; v[6] += f1.z; v[7] += f1.w;
    } else {
        u16x8 hh = *(const u16x8*)(bh + base);
        u16x8 ll = *(const u16x8*)(bh + blo + base);
        for (int j = 0; j < 8; ++j) v[j] += bf2f(hh[j]) + bf2f(ll[j]);
    }
    float s = 0.f, sq = 0.f;
    for (int j = 0; j < 8; ++j) { s += v[j]; sq += v[j] * v[j]; }
    for (int m = 1; m < 64; m <<= 1) { s += __shfl_xor(s, m); sq += __shfl_xor(sq, m); }
    const float mu = s * (1.f / 512.f);
    const float var = fmaxf(sq * (1.f / 512.f) - mu * mu, 0.f);
    const float rs = rsqrtf(var + 1e-5f);
    float4 ga = *(const float4*)(g + lane * 8);
    float4 gb = *(const float4*)(g + lane * 8 + 4);
    float4 ba = *(const float4*)(be + lane * 8);
    float4 bb = *(const float4*)(be + lane * 8 + 4);
    float gg[8] = {ga.x, ga.y, ga.z, ga.w, gb.x, gb.y, gb.z, gb.w};
    float bv[8] = {ba.x, ba.y, ba.z, ba.w, bb.x, bb.y, bb.z, bb.w};
    float o[8];
    for (int j = 0; j < 8; ++j) o[j] = (v[j] - mu) * rs * gg[j] + bv[j];
    if (of) {
        *(float4*)(of + base)     = make_float4(o[0], o[1], o[2], o[3]);
        *(float4*)(of + base + 4) = make_float4(o[4], o[5], o[6], o[7]);
    }
    if (oh) {
        u16x8 h8, l8;
        for (int j = 0; j < 8; ++j) { u16 hh, ll; split2(o[j], hh, ll); h8[j] = hh; l8[j] = ll; }
        *(u16x8*)(oh + base) = h8;
        *(u16x8*)(oh + olo + base) = l8;
    }
}

// Routing from hi/lo planes (argmax of logits). One wave per token.
__global__ __launch_bounds__(256) void route_p(
    const u16* __restrict__ xh, long xlo,
    const float* __restrict__ gw, const float* __restrict__ gb,
    int* __restrict__ idx)
{
    const int tid = threadIdx.x, lane = tid & 63, w = tid >> 6;
    const long row = (long)blockIdx.x * 4 + w;
    const long base = row * 512 + lane * 8;
    u16x8 hh = *(const u16x8*)(xh + base);
    u16x8 ll = *(const u16x8*)(xh + xlo + base);
    float xf[8];
    for (int j = 0; j < 8; ++j) xf[j] = bf2f(hh[j]) + bf2f(ll[j]);
    float d0 = 0.f, d1 = 0.f, d2 = 0.f, d3 = 0.f;
    {
        float4 w0 = *(const float4*)(gw + 0 * 512 + lane * 8);
        float4 w1 = *(const float4*)(gw + 0 * 512 + lane * 8 + 4);
        float wf[8] = {w0.x, w0.y, w0.z, w0.w, w1.x, w1.y, w1.z, w1.w};
        for (int j = 0; j < 8; ++j) d0 += xf[j] * wf[j];
    }
    {
        float4 w0 = *(const float4*)(gw + 1 * 512 + lane * 8);
        float4 w1 = *(const float4*)(gw + 1 * 512 + lane * 8 + 4);
        float wf[8] = {w0.x, w0.y, w0.z, w0.w, w1.x, w1.y, w1.z, w1.w};
        for (int j = 0; j < 8; ++j) d1 += xf[j] * wf[j];
    }
    {
        float4 w0 = *(const float4*)(gw + 2 * 512 + lane * 8);
        float4 w1 = *(const float4*)(gw + 2 * 512 + lane * 8 + 4);
        float wf[8] = {w0.x, w0.y, w0.z, w0.w, w1.x, w1.y, w1.z, w1.w};
        for (int j = 0; j < 8; ++j) d2 += xf[j] * wf[j];
    }
    {
        float4 w0 = *(const float4*)(gw + 3 * 512 + lane * 8);
        float4 w1 = *(const float4*)(gw + 3 * 512 + lane * 8 + 4);
        float wf[8] = {w0.x, w0.y, w0.z, w0.w, w1.x, w1.y, w1.z, w1.w};
        for (int j = 0; j < 8; ++j) d3 += xf[j] * wf[j];
    }
    for (int m = 1; m < 64; m <<= 1) {
        d0 += __shfl_xor(d0, m);
        d1 += __shfl_xor(d1, m);
        d2 += __shfl_xor(d2, m);
        d3 += __shfl_xor(d3, m);
    }
    if (lane == 0) {
        d0 += gb[0]; d1 += gb[1]; d2 += gb[2]; d3 += gb[3];
        float best = d0; int bi = 0;
        if (d1 > best) { best = d1; bi = 1; }
        if (d2 > best) { best = d2; bi = 2; }
        if (d3 > best) { best = d3; bi = 3; }
        idx[row] = bi;
    }
}

// Count idx + lay out expert regions. Single wave.
__global__ void plan_k(const int* __restrict__ idx, int* __restrict__ cursors,
                       int* __restrict__ tile_expert)
{
    int c0 = 0, c1 = 0, c2 = 0, c3 = 0;
    for (int i = threadIdx.x; i < 8192; i += 64) {
        const int e = idx[i];
        c0 += (e == 0); c1 += (e == 1); c2 += (e == 2); c3 += (e == 3);
    }
    for (int m = 1; m < 64; m <<= 1) {
        c0 += __shfl_xor(c0, m);
        c1 += __shfl_xor(c1, m);
        c2 += __shfl_xor(c2, m);
        c3 += __shfl_xor(c3, m);
    }
    if (threadIdx.x == 0) {
        int counts[4] = {c0, c1, c2, c3};
        int off = 0;
        for (int e = 0; e < 4; ++e) {
            cursors[e] = off;
            int nt = (counts[e] + 63) >> 6;
            int t0 = off >> 6;
            for (int i = 0; i < nt; ++i) tile_expert[t0 + i] = e;
            off += nt << 6;
        }
        for (int t = off >> 6; t < 132; ++t) tile_expert[t] = -1;
    }
}

// Scatter: per-block LDS histogram; one global atomic per block per expert.
__global__ __launch_bounds__(256) void scatter_k(
    const int* __restrict__ idx, int* __restrict__ cursors, int* __restrict__ perm)
{
    __shared__ int lcnt[4];
    __shared__ int lbase[4];
    const int t = blockIdx.x * 256 + threadIdx.x;
    if (threadIdx.x < 4) lcnt[threadIdx.x] = 0;
    __syncthreads();
    const int e = idx[t];
    const int lr = atomicAdd(&lcnt[e], 1);
    __syncthreads();
    if (threadIdx.x < 4)
        lbase[threadIdx.x] = atomicAdd(&cursors[threadIdx.x], lcnt[threadIdx.x]);
    __syncthreads();
    perm[lbase[e] + lr] = t;
}

// ===========================================================================
// R17: R16 plan with gemm128_s (128^2 tile) on the three dense 1-term GEMMs
// (QKV, crossQ, crossKV); gemm1_s for MoE; gemm_s for 3-term out-projs.
// ===========================================================================
extern "C" void kernel_launch(void* const* d_in, const int* in_sizes, int n_in,
                              void* d_out, int out_size, void* d_ws, size_t ws_size,
                              hipStream_t stream)
{
    (void)in_sizes; (void)n_in; (void)out_size; (void)ws_size;
    const float* x        = (const float*)d_in[0];
    const float* mem      = (const float*)d_in[1];
    const float* sa_in_w  = (const float*)d_in[2];
    const float* sa_in_b  = (const float*)d_in[3];
    const float* sa_out_w = (const float*)d_in[4];
    const float* sa_out_b = (const float*)d_in[5];
    const float* ca_in_w  = (const float*)d_in[6];
    const float* ca_in_b  = (const float*)d_in[7];
    const float* ca_out_w = (const float*)d_in[8];
    const float* ca_out_b = (const float*)d_in[9];
    const float* gate_w   = (const float*)d_in[10];
    const float* gate_b   = (const float*)d_in[11];
    const float* w1       = (const float*)d_in[12];
    const float* b1       = (const float*)d_in[13];
    const float* w2       = (const float*)d_in[14];
    const float* b2       = (const float*)d_in[15];
    const float* ln1_g    = (const float*)d_in[16];
    const float* ln1_b    = (const float*)d_in[17];
    const float* ln2_g    = (const float*)d_in[18];
    const float* ln2_b    = (const float*)d_in[19];
    const float* ln3_g    = (const float*)d_in[20];
    const float* ln3_b    = (const float*)d_in[21];

    const float sc = 0.125f * 1.4426950408889634f;
    dim3 blk(256, 1, 1);
    char* ws = (char*)d_ws;

    const long WAe_sa_in = 0, WAe_sa_out = 1572864, WAe_ca_in = 2097152, WAe_ca_out = 3670016;

    // -------- proven R5/R13 layout --------
    u16* WA   = (u16*)(ws);
    u16* w1h  = (u16*)(ws + 8388608L);
    u16* w2h  = (u16*)(ws + 16777216L);
    u16* QKVp = (u16*)(ws + 25165824L);
    u16* Op   = (u16*)(ws + 50331648L);
    u16* P1p  = (u16*)(ws + 67108864L);
    float* ymoe = (float*)(ws + 67108864L);
    u16* X1p  = (u16*)(ws + 83886080L);
    int* idx    = (int*)(ws + 100663296L);
    int* perm   = (int*)(ws + 100663296L + 32768);
    int* cursors= (int*)(ws + 100663296L + 32768 + 33792 + 16);
    int* tile_e = (int*)(ws + 100663296L + 32768 + 33792 + 32);

    const long T    = 4194304;
    const long L_8K = 4194304;

    hipMemsetAsync(perm, 0xFF, 8448 * 4, stream);

    split_k<<<dim3(384), blk, 0, stream>>>(sa_in_w,  WA + WAe_sa_in,  WA + WAe_sa_in + 786432, 786432);
    split_k<<<dim3(128), blk, 0, stream>>>(sa_out_w, WA + WAe_sa_out, WA + WAe_sa_out + 262144, 262144);
    split_k<<<dim3(384), blk, 0, stream>>>(ca_in_w,  WA + WAe_ca_in,  WA + WAe_ca_in + 786432, 786432);
    split_k<<<dim3(128), blk, 0, stream>>>(ca_out_w, WA + WAe_ca_out, WA + WAe_ca_out + 262144, 262144);
    splitT_k<<<dim3(32, 8, 4), blk, 0, stream>>>(w1, w1h, 512, 2048);
    splitT_k<<<dim3(8, 32, 4), blk, 0, stream>>>(w2, w2h, 2048, 512);

    // ---- self attention: 128^2 QKV + single z=4 attn ----
    gemm128_s<<<dim3(64, 12), blk, 0, stream>>>(
        x, nullptr, 512, WA + WAe_sa_in, 512, sa_in_b,
        QKVp, 512, 9, T, 512);
    attn_p<<<dim3(32, 8, 4), blk, 0, stream>>>(
        QKVp, QKVp + T, QKVp + 2 * T, 0, Op, L_8K, 0, sc);
    gemm_s<<<dim3(128, 8), blk, 0, stream>>>(
        nullptr, Op, Op + L_8K, 512, 1, nullptr,
        WA + WAe_sa_out, WA + WAe_sa_out + 262144, 512, 0, nullptr,
        sa_out_b, 0, nullptr, 0, nullptr,
        P1p, L_8K, 512, 9, 0, 512, 0);
    ln_p<<<dim3(2048), blk, 0, stream>>>(x, nullptr, 0, nullptr, P1p, L_8K,
                                         ln1_g, ln1_b, nullptr, X1p, L_8K);

    // ---- cross attention ----
    gemm128_s<<<dim3(64, 4), blk, 0, stream>>>(
        nullptr, X1p, 512, WA + WAe_ca_in, 512, ca_in_b,
        QKVp, 512, 9, T, 512);                          // Q -> tensor 0
    gemm128_s<<<dim3(64, 8), blk, 0, stream>>>(
        mem, nullptr, 512, WA + WAe_ca_in + 262144, 512, ca_in_b + 512,
        QKVp + T, 512, 9, T, 512);                      // K,V -> tensors 1,2
    attn_p<<<dim3(32, 8, 4), blk, 0, stream>>>(
        QKVp, QKVp + T, QKVp + 2 * T, 0, Op, L_8K, 0, sc);
    gemm_s<<<dim3(128, 8), blk, 0, stream>>>(
        nullptr, Op, Op + L_8K, 512, 1, nullptr,
        WA + WAe_ca_out, WA + WAe_ca_out + 262144, 512, 0, nullptr,
        ca_out_b, 0, nullptr, 0, nullptr,
        P1p, L_8K, 512, 9, 0, 512, 0);
    ln_p<<<dim3(2048), blk, 0, stream>>>(nullptr, X1p, L_8K, nullptr, P1p, L_8K,
                                         ln2_g, ln2_b, nullptr, X1p, L_8K);

    // ---- MoE (top-1, grouped; proven 2x66-tile chunking, H in QKVp) ----
    route_p<<<dim3(2048), blk, 0, stream>>>(X1p, L_8K, gate_w, gate_b, idx);
    plan_k<<<dim3(1), dim3(64), 0, stream>>>(idx, cursors, tile_e);
    scatter_k<<<dim3(32), blk, 0, stream>>>(idx, cursors, perm);
    for (int c = 0; c < 2; ++c) {
        const int t0 = c * 66;
        gemm1_s<<<dim3(66, 32), blk, 0, stream>>>(
            nullptr, X1p, 512, perm + t0 * 64,
            w1h, 512, 1048576, tile_e + t0,
            b1, 2048, nullptr, 0, nullptr,
            QKVp, 2048, 31, 0, 512, 1);
        gemm1_s<<<dim3(66, 8), blk, 0, stream>>>(
            nullptr, QKVp, 2048, nullptr,
            w2h, 2048, 1048576, tile_e + t0,
            b2, 512, ymoe, 512, perm + t0 * 64,
            nullptr, 0, 31, 0, 2048, 0);
    }
    ln_p<<<dim3(2048), blk, 0, stream>>>(nullptr, X1p, L_8K, ymoe, nullptr, 0,
                                         ln3_g, ln3_b, (float*)d_out, nullptr, 0);
}